// Round 3
// baseline (7985.770 us; speedup 1.0000x reference)
//
#include <hip/hip_runtime.h>
#include <stdint.h>

// Problem constants
constexpr int N  = 20000;    // nodes
constexpr int E  = 320000;   // edges
constexpr int H  = 256;      // hidden
constexpr int FEAT = 64;     // FE == FV
constexpr int NL = 4;        // layers
constexpr int FL = 1024;

constexpr int TM = 64;       // edge GEMM row tile

// ---------------- bf16 helpers (manual, RNE) ----------------
__device__ __forceinline__ float bf2f(unsigned short u) {
    union { uint32_t i; float f; } v; v.i = ((uint32_t)u) << 16; return v.f;
}
__device__ __forceinline__ unsigned short f2bf(float f) {
    union { uint32_t i; float f; } v; v.f = f;
    uint32_t r = v.i + 0x7FFFu + ((v.i >> 16) & 1u);
    return (unsigned short)(r >> 16);
}
__device__ __forceinline__ float4 zf4() { return make_float4(0.f, 0.f, 0.f, 0.f); }
__device__ __forceinline__ float sigmf(float x) { return 1.f / (1.f + __expf(-x)); }
__device__ __forceinline__ float tanhf_(float x) { return 2.f / (1.f + __expf(-2.f * x)) - 1.f; }

// order-preserving float<->u32 encoding (for atomic max over signed floats)
__device__ __forceinline__ unsigned int encf(float x) {
    unsigned int u = __float_as_uint(x);
    return (u & 0x80000000u) ? ~u : (u | 0x80000000u);
}
__device__ __forceinline__ float decf(unsigned int k) {
    unsigned int u = (k & 0x80000000u) ? (k ^ 0x80000000u) : ~k;
    return __uint_as_float(u);
}

#define ST4(S, lk, lr, v) do { S[(lk)+0][lr]=(v).x; S[(lk)+1][lr]=(v).y; \
                               S[(lk)+2][lr]=(v).z; S[(lk)+3][lr]=(v).w; } while(0)

// ---------------- K0: fuse fin+out linear layers ----------------
__global__ void k_fuse_final(const float* __restrict__ fin_w, const float* __restrict__ fin_b,
                             const float* __restrict__ out_w, const float* __restrict__ out_b,
                             float* __restrict__ w_fo) {
    int h = threadIdx.x;
    float acc = 0.f;
    for (int f = 0; f < FL; ++f) acc = fmaf(out_w[f], fin_w[(size_t)f * H + h], acc);
    w_fo[h] = acc;
    if (h == 0) {
        float b = 0.f;
        for (int f = 0; f < FL; ++f) b = fmaf(out_w[f], fin_b[f], b);
        w_fo[H] = b + out_b[0];
    }
}

// ---------------- CSR build (dual: by src and by dst) ----------------
__global__ void k_zero_int(int* __restrict__ p, int n) {
    int i = blockIdx.x * 256 + threadIdx.x;
    if (i < n) p[i] = 0;
}
__global__ void k_hist2(const int* __restrict__ src, const int* __restrict__ dst,
                        int* __restrict__ curS, int* __restrict__ curD) {
    int e = blockIdx.x * 256 + threadIdx.x;
    if (e < E) { atomicAdd(&curS[src[e]], 1); atomicAdd(&curD[dst[e]], 1); }
}
// in-place: cur[] holds degrees on entry, running start-offsets on exit
__global__ void k_scan(int* __restrict__ cur) {
    __shared__ int cs[256];
    int t = threadIdx.x;
    constexpr int CH = (N + 255) / 256;
    int beg = t * CH, end = min(beg + CH, N);
    int s = 0;
    for (int i = beg; i < end; ++i) s += cur[i];
    cs[t] = s;
    __syncthreads();
    for (int off = 1; off < 256; off <<= 1) {
        int v = cs[t];
        int u = (t >= off) ? cs[t - off] : 0;
        __syncthreads();
        cs[t] = v + u;
        __syncthreads();
    }
    int run = (t > 0) ? cs[t - 1] : 0;
    for (int i = beg; i < end; ++i) { int d = cur[i]; cur[i] = run; run += d; }
}
__global__ void k_fill_pair(const int* __restrict__ src, const int* __restrict__ dst,
                            int* __restrict__ curS, int* __restrict__ curD,
                            int* __restrict__ adjS, int* __restrict__ adjD) {
    int e = blockIdx.x * 256 + threadIdx.x;
    if (e < E) {
        int p = atomicAdd(&curS[src[e]], 1); adjS[p] = e;
        int q = atomicAdd(&curD[dst[e]], 1); adjD[q] = e;
    }
    // after this kernel, curS[v]/curD[v] are END offsets of node v
}

__global__ void k_fill_u32(unsigned int* __restrict__ p, unsigned int val) {
    size_t i = ((size_t)blockIdx.x * 256 + threadIdx.x) * 4;
    uint4 v = make_uint4(val, val, val, val);
    *(uint4*)(p + i) = v;
}
__global__ void k_zero_stats(double* __restrict__ stats) {
    int i = blockIdx.x * 256 + threadIdx.x;
    if (i < 1024) stats[i] = 0.0;
}

// ---------------- input projections: C[M,256] = A[M,64] @ W[256,64].T + b (bf16 out) ----------------
__global__ __launch_bounds__(256) void k_in_proj(const float* __restrict__ A, const float* __restrict__ W,
                                                 const float* __restrict__ bias,
                                                 unsigned short* __restrict__ C, int M) {
    __shared__ float As[16][FEAT];
    int t = threadIdx.x;
    int row0 = blockIdx.x * 16;
    int lr = t >> 4, ls = t & 15;
    if (row0 + lr < M)
        ((float4*)&As[lr][0])[ls] = ((const float4*)(A + (size_t)(row0 + lr) * FEAT))[ls];
    else
        ((float4*)&As[lr][0])[ls] = zf4();
    __syncthreads();
    int h = t;
    float acc[16];
#pragma unroll
    for (int i = 0; i < 16; ++i) acc[i] = 0.f;
    const float4* w4 = (const float4*)(W + (size_t)h * FEAT);
    for (int k4 = 0; k4 < 16; ++k4) {
        float4 wv = w4[k4];
        int kb = k4 * 4;
#pragma unroll
        for (int i = 0; i < 16; ++i) {
            float4 a = *(const float4*)&As[i][kb];
            acc[i] = fmaf(a.x, wv.x, acc[i]);
            acc[i] = fmaf(a.y, wv.y, acc[i]);
            acc[i] = fmaf(a.z, wv.z, acc[i]);
            acc[i] = fmaf(a.w, wv.w, acc[i]);
        }
    }
    float bv = bias[h];
    int mrows = min(16, M - row0);
    for (int i = 0; i < mrows; ++i)
        C[(size_t)(row0 + i) * H + h] = f2bf(acc[i] + bv);
}

// ---------------- node GEMM: vp = v_in @ W.T (bf16 in/out, fp32 math; Lv_b cancels in BN) ----------------
__global__ __launch_bounds__(256) void k_gemm_node(const unsigned short* __restrict__ A,
                                                   const float* __restrict__ W,
                                                   unsigned short* __restrict__ C) {
    constexpr int TN = 128;
    __shared__ float As[16][TM + 4];
    __shared__ float Bs[16][TN + 4];
    int t = threadIdx.x;
    int row0 = blockIdx.x * TM, col0 = blockIdx.y * TN;
    int rg = t >> 4, cg = t & 15;
    int lar = t >> 2, lak = (t & 3) << 2;
    int lbj = t >> 1, lbk = (t & 1) << 3;
    bool arow = (row0 + lar) < N;
    float acc[4][8];
#pragma unroll
    for (int i = 0; i < 4; ++i)
#pragma unroll
        for (int c = 0; c < 8; ++c) acc[i][c] = 0.f;
    const unsigned short* aptr = A + (size_t)(row0 + lar) * H + lak;
    const float* bptr = W + (size_t)(col0 + lbj) * H + lbk;
    for (int k0 = 0; k0 < H; k0 += 16) {
        ushort4 a4u = arow ? *(const ushort4*)(aptr + k0) : make_ushort4(0, 0, 0, 0);
        float4 b0 = *(const float4*)(bptr + k0);
        float4 b1 = *(const float4*)(bptr + k0 + 4);
        __syncthreads();
        As[lak + 0][lar] = bf2f(a4u.x);
        As[lak + 1][lar] = bf2f(a4u.y);
        As[lak + 2][lar] = bf2f(a4u.z);
        As[lak + 3][lar] = bf2f(a4u.w);
        ST4(Bs, lbk, lbj, b0);
        ST4(Bs, lbk + 4, lbj, b1);
        __syncthreads();
#pragma unroll
        for (int kk = 0; kk < 16; ++kk) {
            float4 av  = *(const float4*)&As[kk][rg << 2];
            float4 bv0 = *(const float4*)&Bs[kk][cg << 3];
            float4 bv1 = *(const float4*)&Bs[kk][(cg << 3) + 4];
            float a_[4] = {av.x, av.y, av.z, av.w};
            float b_[8] = {bv0.x, bv0.y, bv0.z, bv0.w, bv1.x, bv1.y, bv1.z, bv1.w};
#pragma unroll
            for (int c = 0; c < 8; ++c) {
                acc[0][c] = fmaf(a_[0], b_[c], acc[0][c]);
                acc[1][c] = fmaf(a_[1], b_[c], acc[1][c]);
                acc[2][c] = fmaf(a_[2], b_[c], acc[2][c]);
                acc[3][c] = fmaf(a_[3], b_[c], acc[3][c]);
            }
        }
    }
    int rmax = N - row0;
#pragma unroll
    for (int i = 0; i < 4; ++i) {
        int r = (rg << 2) + i;
        if (r < rmax) {
            unsigned short* cp = C + (size_t)(row0 + r) * H + col0 + (cg << 3);
            *(ushort4*)cp       = make_ushort4(f2bf(acc[i][0]), f2bf(acc[i][1]), f2bf(acc[i][2]), f2bf(acc[i][3]));
            *(ushort4*)(cp + 4) = make_ushort4(f2bf(acc[i][4]), f2bf(acc[i][5]), f2bf(acc[i][6]), f2bf(acc[i][7]));
        }
    }
}

// ---------------- edge pass: CSR-ordered GEMM + raw scatter-max (+ stats | + residual) ----------------
// raw = e_in@Le^T + vp[src] + vp[dst].  FIRST (dst CSR): BN stats + raw max.
// !FIRST (src CSR): raw max + e_in += relu(affine(raw)) in place (tile owns its rows).
template <bool FIRST>
__global__ __launch_bounds__(256) void k_edge_pass(const unsigned short* __restrict__ ein,
                                                   const float* __restrict__ W,
                                                   const unsigned short* __restrict__ vp,
                                                   const int* __restrict__ src, const int* __restrict__ dst,
                                                   const int* __restrict__ adj, const int* __restrict__ endo,
                                                   unsigned int* __restrict__ vie,
                                                   double* __restrict__ stats,
                                                   const float* __restrict__ scale, const float* __restrict__ shift,
                                                   unsigned short* __restrict__ ein_rw) {
    __shared__ float As[16][TM + 4];
    __shared__ float Bs[16][H + 4];
    __shared__ float praw[TM][128 + 4];
    __shared__ int s_edge[TM], s_node[TM], s_src[TM], s_dst[TM];
    __shared__ float csum[H], csq[H];
    int t = threadIdx.x;
    int p0 = blockIdx.x * TM;
    if (t < TM) {
        int e = adj[p0 + t];
        s_edge[t] = e;
        s_src[t] = src[e];
        s_dst[t] = dst[e];
        // node of adj position p: smallest v with endo[v] > p
        int lo = 0, hi = N - 1, p = p0 + t;
        while (lo < hi) { int mid = (lo + hi) >> 1; if (endo[mid] > p) hi = mid; else lo = mid + 1; }
        s_node[t] = lo;
    }
    if (FIRST) { csum[t] = 0.f; csq[t] = 0.f; }
    __syncthreads();

    int rg = t >> 5;        // 0..7 -> rows rg*8..rg*8+7
    int cg = t & 31;        // cols cg + 32*j, j=0..7
    int lar = t >> 2, lak = (t & 3) << 2;
    float acc[8][8];
#pragma unroll
    for (int i = 0; i < 8; ++i)
#pragma unroll
        for (int j = 0; j < 8; ++j) acc[i][j] = 0.f;

    const unsigned short* arow = ein + (size_t)s_edge[lar] * H + lak;
    const float* wrow = W + (size_t)t * H;
    for (int k0 = 0; k0 < H; k0 += 16) {
        ushort4 a4u = *(const ushort4*)(arow + k0);
        float4 b0 = *(const float4*)(wrow + k0);
        float4 b1 = *(const float4*)(wrow + k0 + 4);
        float4 b2 = *(const float4*)(wrow + k0 + 8);
        float4 b3 = *(const float4*)(wrow + k0 + 12);
        __syncthreads();
        As[lak + 0][lar] = bf2f(a4u.x);
        As[lak + 1][lar] = bf2f(a4u.y);
        As[lak + 2][lar] = bf2f(a4u.z);
        As[lak + 3][lar] = bf2f(a4u.w);
        ST4(Bs, 0, t, b0);
        ST4(Bs, 4, t, b1);
        ST4(Bs, 8, t, b2);
        ST4(Bs, 12, t, b3);
        __syncthreads();
#pragma unroll
        for (int kk = 0; kk < 16; ++kk) {
            float4 av0 = *(const float4*)&As[kk][rg << 3];
            float4 av1 = *(const float4*)&As[kk][(rg << 3) + 4];
            float a_[8] = {av0.x, av0.y, av0.z, av0.w, av1.x, av1.y, av1.z, av1.w};
            float b_[8];
#pragma unroll
            for (int j = 0; j < 8; ++j) b_[j] = Bs[kk][cg + (j << 5)];
#pragma unroll
            for (int i = 0; i < 8; ++i)
#pragma unroll
                for (int j = 0; j < 8; ++j) acc[i][j] = fmaf(a_[i], b_[j], acc[i][j]);
        }
    }
    // epilogue: add u = vp[src]+vp[dst]
#pragma unroll
    for (int i = 0; i < 8; ++i) {
        int r = (rg << 3) + i;
        const unsigned short* vs = vp + (size_t)s_src[r] * H;
        const unsigned short* vd = vp + (size_t)s_dst[r] * H;
#pragma unroll
        for (int j = 0; j < 8; ++j) {
            int col = cg + (j << 5);
            acc[i][j] += bf2f(vs[col]) + bf2f(vd[col]);
        }
    }
    if (FIRST) {
#pragma unroll
        for (int j = 0; j < 8; ++j) {
            float s = 0.f, q = 0.f;
#pragma unroll
            for (int i = 0; i < 8; ++i) { s += acc[i][j]; q += acc[i][j] * acc[i][j]; }
            atomicAdd(&csum[cg + (j << 5)], s);
            atomicAdd(&csq[cg + (j << 5)], q);
        }
    }
    // segmented max over node runs, 128 cols at a time
    for (int half = 0; half < 2; ++half) {
        __syncthreads();
#pragma unroll
        for (int i = 0; i < 8; ++i)
#pragma unroll
            for (int jj = 0; jj < 4; ++jj)
                praw[(rg << 3) + i][cg + (jj << 5)] = acc[i][(half << 2) + jj];
        __syncthreads();
        if (t < 128) {
            int gcol = (half << 7) + t;
            int cur = s_node[0];
            float m = praw[0][t];
            for (int r = 1; r < TM; ++r) {
                int nd = s_node[r];
                float v = praw[r][t];
                if (nd != cur) {
                    atomicMax(&vie[(size_t)cur * H + gcol], encf(m));
                    cur = nd; m = v;
                } else m = fmaxf(m, v);
            }
            atomicMax(&vie[(size_t)cur * H + gcol], encf(m));
        }
    }
    if (FIRST) {
        __syncthreads();
        atomicAdd(&stats[t], (double)csum[t]);
        atomicAdd(&stats[256 + t], (double)csq[t]);
    } else {
        float sc[8], sh[8];
#pragma unroll
        for (int j = 0; j < 8; ++j) { sc[j] = scale[cg + (j << 5)]; sh[j] = shift[cg + (j << 5)]; }
#pragma unroll
        for (int i = 0; i < 8; ++i) {
            int r = (rg << 3) + i;
            unsigned short* pr = ein_rw + (size_t)s_edge[r] * H;
#pragma unroll
            for (int j = 0; j < 8; ++j) {
                int col = cg + (j << 5);
                float y = fmaxf(fmaf(acc[i][j], sc[j], sh[j]), 0.f);
                pr[col] = f2bf(bf2f(pr[col]) + y);
            }
        }
    }
}

// ---------------- BN finalize: y = x*scale + shift ----------------
__global__ void k_bn_final(const double* __restrict__ stats, int base,
                           const float* __restrict__ g, const float* __restrict__ b,
                           double cnt, float* __restrict__ scale, float* __restrict__ shift) {
    int j = threadIdx.x;
    double m = stats[base + j] / cnt;
    double var = stats[base + 256 + j] / cnt - m * m;
    if (var < 0.0) var = 0.0;
    float inv = rsqrtf((float)var + 1e-5f);
    float sc = g[j] * inv;
    scale[j] = sc;
    shift[j] = b[j] - (float)m * sc;
}

// ---------------- vie finalize: decode raw max, affine+relu; untouched (isolated) -> 0 ----------------
__global__ void k_vie_final(unsigned int* __restrict__ vie_u,
                            const float* __restrict__ scale, const float* __restrict__ shift) {
    size_t idx = ((size_t)blockIdx.x * 256 + threadIdx.x) * 4;
    int col = (int)(idx & (size_t)(H - 1));
    uint4 u = *(const uint4*)(vie_u + idx);
    float4 sc = *(const float4*)(scale + col);
    float4 sh = *(const float4*)(shift + col);
    float4 o;
    o.x = (u.x == 0u) ? 0.f : fmaxf(fmaf(decf(u.x), sc.x, sh.x), 0.f);
    o.y = (u.y == 0u) ? 0.f : fmaxf(fmaf(decf(u.y), sc.y, sh.y), 0.f);
    o.z = (u.z == 0u) ? 0.f : fmaxf(fmaf(decf(u.z), sc.z, sh.z), 0.f);
    o.w = (u.w == 0u) ? 0.f : fmaxf(fmaf(decf(u.w), sc.w, sh.w), 0.f);
    *(float4*)((float*)vie_u + idx) = o;
}

// ---------------- fused GRU: h = (1-z)*n + z*v_in, plus BN stats ----------------
__global__ __launch_bounds__(256) void k_gru(const float* __restrict__ vie, const unsigned short* __restrict__ vin,
                                             const float* __restrict__ wih, const float* __restrict__ whh,
                                             const float* __restrict__ bih, const float* __restrict__ bhh,
                                             unsigned short* __restrict__ hout, double* __restrict__ stats) {
    constexpr int TN = 64;
    __shared__ float Ai[16][TM + 4], Ah[16][TM + 4];
    __shared__ float Br[16][TN + 4], Bz[16][TN + 4], Bg[16][TN + 4];
    __shared__ float Cr[16][TN + 4], Cz[16][TN + 4], Cg[16][TN + 4];
    __shared__ float csum[TN], csq[TN];
    int t = threadIdx.x;
    int row0 = blockIdx.x * TM, col0 = blockIdx.y * TN;
    if (t < TN) { csum[t] = 0.f; csq[t] = 0.f; }
    int rg = t >> 4, cg = t & 15;
    int lr = t >> 2, lk = (t & 3) << 2;
    bool arow = (row0 + lr) < N;
    float ar[4][4], az[4][4], ag[4][4], ah[4][4];
#pragma unroll
    for (int i = 0; i < 4; ++i)
#pragma unroll
        for (int c = 0; c < 4; ++c) { ar[i][c] = 0.f; az[i][c] = 0.f; ag[i][c] = 0.f; ah[i][c] = 0.f; }
    const float* aip = vie + (size_t)(row0 + lr) * H + lk;
    const unsigned short* ahp = vin + (size_t)(row0 + lr) * H + lk;
    const float* brp = wih + (size_t)(col0 + lr) * H + lk;
    const float* bzp = wih + (size_t)(256 + col0 + lr) * H + lk;
    const float* bgp = wih + (size_t)(512 + col0 + lr) * H + lk;
    const float* crp = whh + (size_t)(col0 + lr) * H + lk;
    const float* czp = whh + (size_t)(256 + col0 + lr) * H + lk;
    const float* cgp = whh + (size_t)(512 + col0 + lr) * H + lk;
    for (int k0 = 0; k0 < H; k0 += 16) {
        float4 va = arow ? *(const float4*)(aip + k0) : zf4();
        ushort4 vhu = arow ? *(const ushort4*)(ahp + k0) : make_ushort4(0, 0, 0, 0);
        float4 wr = *(const float4*)(brp + k0);
        float4 wz = *(const float4*)(bzp + k0);
        float4 wg = *(const float4*)(bgp + k0);
        float4 ur = *(const float4*)(crp + k0);
        float4 uz = *(const float4*)(czp + k0);
        float4 ug = *(const float4*)(cgp + k0);
        __syncthreads();
        ST4(Ai, lk, lr, va);
        Ah[lk + 0][lr] = bf2f(vhu.x);
        Ah[lk + 1][lr] = bf2f(vhu.y);
        Ah[lk + 2][lr] = bf2f(vhu.z);
        Ah[lk + 3][lr] = bf2f(vhu.w);
        ST4(Br, lk, lr, wr); ST4(Bz, lk, lr, wz); ST4(Bg, lk, lr, wg);
        ST4(Cr, lk, lr, ur); ST4(Cz, lk, lr, uz); ST4(Cg, lk, lr, ug);
        __syncthreads();
#pragma unroll
        for (int kk = 0; kk < 16; ++kk) {
            float4 xa = *(const float4*)&Ai[kk][rg << 2];
            float4 xh = *(const float4*)&Ah[kk][rg << 2];
            float4 r4 = *(const float4*)&Br[kk][cg << 2];
            float4 z4 = *(const float4*)&Bz[kk][cg << 2];
            float4 g4 = *(const float4*)&Bg[kk][cg << 2];
            float4 R4 = *(const float4*)&Cr[kk][cg << 2];
            float4 Z4 = *(const float4*)&Cz[kk][cg << 2];
            float4 G4 = *(const float4*)&Cg[kk][cg << 2];
            float A_[4] = {xa.x, xa.y, xa.z, xa.w};
            float H_[4] = {xh.x, xh.y, xh.z, xh.w};
            float br_[4] = {r4.x, r4.y, r4.z, r4.w}, bz_[4] = {z4.x, z4.y, z4.z, z4.w};
            float bg_[4] = {g4.x, g4.y, g4.z, g4.w};
            float cr_[4] = {R4.x, R4.y, R4.z, R4.w}, cz_[4] = {Z4.x, Z4.y, Z4.z, Z4.w};
            float cg_[4] = {G4.x, G4.y, G4.z, G4.w};
#pragma unroll
            for (int i = 0; i < 4; ++i)
#pragma unroll
                for (int c = 0; c < 4; ++c) {
                    ar[i][c] = fmaf(A_[i], br_[c], fmaf(H_[i], cr_[c], ar[i][c]));
                    az[i][c] = fmaf(A_[i], bz_[c], fmaf(H_[i], cz_[c], az[i][c]));
                    ag[i][c] = fmaf(A_[i], bg_[c], ag[i][c]);
                    ah[i][c] = fmaf(H_[i], cg_[c], ah[i][c]);
                }
        }
    }
    float lsum[4] = {0.f, 0.f, 0.f, 0.f}, lsq[4] = {0.f, 0.f, 0.f, 0.f};
    int rmax = N - row0;
#pragma unroll
    for (int i = 0; i < 4; ++i) {
        int r = (rg << 2) + i;
        bool ok = r < rmax;
        int node = row0 + r;
#pragma unroll
        for (int c = 0; c < 4; ++c) {
            int j = col0 + (cg << 2) + c;
            float rr = sigmf(ar[i][c] + bih[j] + bhh[j]);
            float zz = sigmf(az[i][c] + bih[H + j] + bhh[H + j]);
            float nn = tanhf_(ag[i][c] + bih[2 * H + j] + rr * (ah[i][c] + bhh[2 * H + j]));
            if (ok) {
                float vv = bf2f(vin[(size_t)node * H + j]);
                float hv = (1.f - zz) * nn + zz * vv;
                hout[(size_t)node * H + j] = f2bf(hv);
                lsum[c] += hv; lsq[c] += hv * hv;
            }
        }
    }
#pragma unroll
    for (int c = 0; c < 4; ++c) {
        atomicAdd(&csum[(cg << 2) + c], lsum[c]);
        atomicAdd(&csq[(cg << 2) + c], lsq[c]);
    }
    __syncthreads();
    if (t < TN) {
        atomicAdd(&stats[512 + col0 + t], (double)csum[t]);
        atomicAdd(&stats[768 + col0 + t], (double)csq[t]);
    }
}

// ---------------- vertex update: v_in += relu(h*scale+shift) (bf16 rmw) ----------------
__global__ void k_vertex_update(unsigned short* __restrict__ vin, const unsigned short* __restrict__ h,
                                const float* __restrict__ scale, const float* __restrict__ shift) {
    size_t idx = ((size_t)blockIdx.x * 256 + threadIdx.x) * 4;
    int col = (int)(idx & (size_t)(H - 1));
    ushort4 hv = *(const ushort4*)(h + idx);
    float4 sc = *(const float4*)(scale + col);
    float4 sh = *(const float4*)(shift + col);
    ushort4 vv = *(const ushort4*)(vin + idx);
    float o0 = bf2f(vv.x) + fmaxf(fmaf(bf2f(hv.x), sc.x, sh.x), 0.f);
    float o1 = bf2f(vv.y) + fmaxf(fmaf(bf2f(hv.y), sc.y, sh.y), 0.f);
    float o2 = bf2f(vv.z) + fmaxf(fmaf(bf2f(hv.z), sc.z, sh.z), 0.f);
    float o3 = bf2f(vv.w) + fmaxf(fmaf(bf2f(hv.w), sc.w, sh.w), 0.f);
    *(ushort4*)(vin + idx) = make_ushort4(f2bf(o0), f2bf(o1), f2bf(o2), f2bf(o3));
}

// ---------------- final: out[e] = e_in[e] . w_fo + b_fo ----------------
__global__ __launch_bounds__(256) void k_final(const unsigned short* __restrict__ ein,
                                               const float* __restrict__ w_fo, float* __restrict__ out) {
    int t = threadIdx.x;
    int lane = t & 63;
    int w = (blockIdx.x << 2) + (t >> 6);
    float4 wv = *(const float4*)(w_fo + lane * 4);
    float bfo = w_fo[H];
    int e0 = w * 64;
    for (int e = e0; e < e0 + 64; ++e) {
        ushort4 u = *(const ushort4*)(ein + (size_t)e * H + lane * 4);
        float p = bf2f(u.x) * wv.x + bf2f(u.y) * wv.y + bf2f(u.z) * wv.z + bf2f(u.w) * wv.w;
        for (int off = 32; off > 0; off >>= 1) p += __shfl_down(p, off, 64);
        if (lane == 0) out[e] = p + bfo;
    }
}

// ---------------- host entry ----------------
extern "C" void kernel_launch(void* const* d_in, const int* in_sizes, int n_in,
                              void* d_out, int out_size, void* d_ws, size_t ws_size,
                              hipStream_t stream) {
    (void)in_sizes; (void)n_in; (void)out_size; (void)ws_size;
    const float* x         = (const float*)d_in[0];
    const float* edge_attr = (const float*)d_in[1];
    const int*   ei        = (const int*)d_in[2];
    const int*   src = ei;
    const int*   dst = ei + E;
    const float* ew  = (const float*)d_in[3];
    const float* eb  = (const float*)d_in[4];
    const float* vw  = (const float*)d_in[5];
    const float* vb  = (const float*)d_in[6];
    const float* Le_w = (const float*)d_in[7];
    // d_in[8] = Le_b : cancels in BN
    const float* Lv_w = (const float*)d_in[9];
    // d_in[10] = Lv_b : cancels in BN
    const float* bne_g = (const float*)d_in[11];
    const float* bne_b = (const float*)d_in[12];
    const float* bnv_g = (const float*)d_in[13];
    const float* bnv_b = (const float*)d_in[14];
    const float* gwih  = (const float*)d_in[15];
    const float* gwhh  = (const float*)d_in[16];
    const float* gbih  = (const float*)d_in[17];
    const float* gbhh  = (const float*)d_in[18];
    const float* fin_w = (const float*)d_in[19];
    const float* fin_b = (const float*)d_in[20];
    const float* out_w = (const float*)d_in[21];
    const float* out_b = (const float*)d_in[22];
    float* out = (float*)d_out;

    const size_t nh = (size_t)N * H, eh = (size_t)E * H;
    char* base = (char*)d_ws;
    size_t off = 0;
    auto alloc = [&](size_t bytes) -> char* {
        char* p = base + off;
        off = (off + bytes + 255) & ~(size_t)255;
        return p;
    };
    float* w_fo = (float*)alloc((H + 1) * sizeof(float));
    unsigned short* v_in = (unsigned short*)alloc(nh * sizeof(unsigned short));
    unsigned short* vp   = (unsigned short*)alloc(nh * sizeof(unsigned short));  // aliased as hbuf after edge passes
    unsigned int* vie_u  = (unsigned int*)alloc(nh * sizeof(unsigned int));      // raw max (u32) then fp32 vie
    unsigned short* e_in = (unsigned short*)alloc(eh * sizeof(unsigned short));
    double* stats  = (double*)alloc(1024 * sizeof(double));
    float* scale_e = (float*)alloc(H * sizeof(float));
    float* shift_e = (float*)alloc(H * sizeof(float));
    float* scale_v = (float*)alloc(H * sizeof(float));
    float* shift_v = (float*)alloc(H * sizeof(float));
    int* curS = (int*)alloc((size_t)N * sizeof(int));
    int* curD = (int*)alloc((size_t)N * sizeof(int));
    int* adjS = (int*)alloc((size_t)E * sizeof(int));
    int* adjD = (int*)alloc((size_t)E * sizeof(int));
    unsigned short* hbuf = vp;  // vp dead after edge passes; GRU writes here

    // fused final weights
    k_fuse_final<<<1, 256, 0, stream>>>(fin_w, fin_b, out_w, out_b, w_fo);
    // dual CSR
    k_zero_int<<<(N + 255) / 256, 256, 0, stream>>>(curS, N);
    k_zero_int<<<(N + 255) / 256, 256, 0, stream>>>(curD, N);
    k_hist2<<<E / 256, 256, 0, stream>>>(src, dst, curS, curD);
    k_scan<<<1, 256, 0, stream>>>(curS);
    k_scan<<<1, 256, 0, stream>>>(curD);
    k_fill_pair<<<E / 256, 256, 0, stream>>>(src, dst, curS, curD, adjS, adjD);
    // input projections (bf16 out)
    k_in_proj<<<N / 16, 256, 0, stream>>>(x, vw, vb, v_in, N);
    k_in_proj<<<E / 16, 256, 0, stream>>>(edge_attr, ew, eb, e_in, E);

    const int ntile = (N + TM - 1) / TM;
    for (int k = 0; k < NL; ++k) {
        k_zero_stats<<<4, 256, 0, stream>>>(stats);
        k_fill_u32<<<(int)(nh / 4 / 256), 256, 0, stream>>>(vie_u, 0u);
        k_gemm_node<<<dim3(ntile, 2), 256, 0, stream>>>(v_in, Lv_w + (size_t)k * H * H, vp);
        // dst pass: stats + raw max
        k_edge_pass<true><<<E / TM, 256, 0, stream>>>(e_in, Le_w + (size_t)k * H * H, vp, src, dst,
                                                      adjD, curD, vie_u, stats, nullptr, nullptr, nullptr);
        k_bn_final<<<1, 256, 0, stream>>>(stats, 0, bne_g + k * H, bne_b + k * H, (double)E, scale_e, shift_e);
        // src pass: raw max + residual into e_in
        k_edge_pass<false><<<E / TM, 256, 0, stream>>>(e_in, Le_w + (size_t)k * H * H, vp, src, dst,
                                                       adjS, curS, vie_u, nullptr, scale_e, shift_e, e_in);
        k_vie_final<<<(int)(nh / 4 / 256), 256, 0, stream>>>(vie_u, scale_e, shift_e);
        k_gru<<<dim3(ntile, 4), 256, 0, stream>>>((const float*)vie_u, v_in,
            gwih + (size_t)k * 3 * H * H, gwhh + (size_t)k * 3 * H * H,
            gbih + (size_t)k * 3 * H, gbhh + (size_t)k * 3 * H, hbuf, stats);
        k_bn_final<<<1, 256, 0, stream>>>(stats, 512, bnv_g + k * H, bnv_b + k * H, (double)N, scale_v, shift_v);
        k_vertex_update<<<(int)(nh / 4 / 256), 256, 0, stream>>>(v_in, hbuf, scale_v, shift_v);
    }
    k_final<<<E / 256, 256, 0, stream>>>(e_in, w_fo, out);
}

// Round 4
// 3961.847 us; speedup vs baseline: 2.0157x; 2.0157x over previous
//
#include <hip/hip_runtime.h>
#include <stdint.h>

// Problem constants
constexpr int N  = 20000;    // nodes
constexpr int E  = 320000;   // edges
constexpr int H  = 256;      // hidden
constexpr int FEAT = 64;     // FE == FV
constexpr int NL = 4;        // layers
constexpr int FL = 1024;

constexpr int TM = 64;       // GEMM row tile

typedef unsigned short u16;
typedef short bf16x8 __attribute__((ext_vector_type(8)));
typedef float f32x4 __attribute__((ext_vector_type(4)));

// ---------------- bf16 helpers (manual, RNE) ----------------
__device__ __forceinline__ float bf2f(u16 u) {
    union { uint32_t i; float f; } v; v.i = ((uint32_t)u) << 16; return v.f;
}
__device__ __forceinline__ u16 f2bf(float f) {
    union { uint32_t i; float f; } v; v.f = f;
    uint32_t r = v.i + 0x7FFFu + ((v.i >> 16) & 1u);
    return (u16)(r >> 16);
}
__device__ __forceinline__ float4 zf4() { return make_float4(0.f, 0.f, 0.f, 0.f); }
__device__ __forceinline__ float sigmf(float x) { return 1.f / (1.f + __expf(-x)); }
__device__ __forceinline__ float tanhf_(float x) { return 2.f / (1.f + __expf(-2.f * x)) - 1.f; }

// order-preserving float<->u32 encoding (for atomic max over signed floats)
__device__ __forceinline__ unsigned int encf(float x) {
    unsigned int u = __float_as_uint(x);
    return (u & 0x80000000u) ? ~u : (u | 0x80000000u);
}
__device__ __forceinline__ float decf(unsigned int k) {
    unsigned int u = (k & 0x80000000u) ? (k ^ 0x80000000u) : ~k;
    return __uint_as_float(u);
}

#define ST4(S, lk, lr, v) do { S[(lk)+0][lr]=(v).x; S[(lk)+1][lr]=(v).y; \
                               S[(lk)+2][lr]=(v).z; S[(lk)+3][lr]=(v).w; } while(0)

// ---------------- K0: fuse fin+out linear layers ----------------
__global__ void k_fuse_final(const float* __restrict__ fin_w, const float* __restrict__ fin_b,
                             const float* __restrict__ out_w, const float* __restrict__ out_b,
                             float* __restrict__ w_fo) {
    int h = threadIdx.x;
    float acc = 0.f;
    for (int f = 0; f < FL; ++f) acc = fmaf(out_w[f], fin_w[(size_t)f * H + h], acc);
    w_fo[h] = acc;
    if (h == 0) {
        float b = 0.f;
        for (int f = 0; f < FL; ++f) b = fmaf(out_w[f], fin_b[f], b);
        w_fo[H] = b + out_b[0];
    }
}

// ---------------- weight convert fp32 -> bf16 ----------------
__global__ void k_cvt_w(const float* __restrict__ w, u16* __restrict__ o, int n4) {
    int i = blockIdx.x * 256 + threadIdx.x;
    if (i < n4) {
        float4 v = *(const float4*)(w + (size_t)i * 4);
        *(ushort4*)(o + (size_t)i * 4) = make_ushort4(f2bf(v.x), f2bf(v.y), f2bf(v.z), f2bf(v.w));
    }
}

// ---------------- CSR build (dual: by src and by dst) ----------------
__global__ void k_zero_int(int* __restrict__ p, int n) {
    int i = blockIdx.x * 256 + threadIdx.x;
    if (i < n) p[i] = 0;
}
__global__ void k_zero_f64(double* __restrict__ p, int n) {
    int i = blockIdx.x * 256 + threadIdx.x;
    if (i < n) p[i] = 0.0;
}
__global__ void k_hist2(const int* __restrict__ src, const int* __restrict__ dst,
                        int* __restrict__ curS, int* __restrict__ curD) {
    int e = blockIdx.x * 256 + threadIdx.x;
    if (e < E) { atomicAdd(&curS[src[e]], 1); atomicAdd(&curD[dst[e]], 1); }
}
__global__ void k_scan(int* __restrict__ cur) {
    __shared__ int cs[256];
    int t = threadIdx.x;
    constexpr int CH = (N + 255) / 256;
    int beg = t * CH, end = min(beg + CH, N);
    int s = 0;
    for (int i = beg; i < end; ++i) s += cur[i];
    cs[t] = s;
    __syncthreads();
    for (int off = 1; off < 256; off <<= 1) {
        int v = cs[t];
        int u = (t >= off) ? cs[t - off] : 0;
        __syncthreads();
        cs[t] = v + u;
        __syncthreads();
    }
    int run = (t > 0) ? cs[t - 1] : 0;
    for (int i = beg; i < end; ++i) { int d = cur[i]; cur[i] = run; run += d; }
}
__global__ void k_fill_pair(const int* __restrict__ src, const int* __restrict__ dst,
                            int* __restrict__ curS, int* __restrict__ curD,
                            int* __restrict__ adjS, int* __restrict__ adjD) {
    int e = blockIdx.x * 256 + threadIdx.x;
    if (e < E) {
        int p = atomicAdd(&curS[src[e]], 1); adjS[p] = e;
        int q = atomicAdd(&curD[dst[e]], 1); adjD[q] = e;
    }
    // after this kernel, curS[v]/curD[v] are END offsets of node v
}
__global__ void k_fill_u32(unsigned int* __restrict__ p, unsigned int val) {
    size_t i = ((size_t)blockIdx.x * 256 + threadIdx.x) * 4;
    uint4 v = make_uint4(val, val, val, val);
    *(uint4*)(p + i) = v;
}

// ---------------- input projections: C[M,256] = A[M,64] @ W[256,64].T + b (bf16 out) ----------------
__global__ __launch_bounds__(256) void k_in_proj(const float* __restrict__ A, const float* __restrict__ W,
                                                 const float* __restrict__ bias,
                                                 u16* __restrict__ C, int M) {
    __shared__ float As[16][FEAT];
    int t = threadIdx.x;
    int row0 = blockIdx.x * 16;
    int lr = t >> 4, ls = t & 15;
    if (row0 + lr < M)
        ((float4*)&As[lr][0])[ls] = ((const float4*)(A + (size_t)(row0 + lr) * FEAT))[ls];
    else
        ((float4*)&As[lr][0])[ls] = zf4();
    __syncthreads();
    int h = t;
    float acc[16];
#pragma unroll
    for (int i = 0; i < 16; ++i) acc[i] = 0.f;
    const float4* w4 = (const float4*)(W + (size_t)h * FEAT);
    for (int k4 = 0; k4 < 16; ++k4) {
        float4 wv = w4[k4];
        int kb = k4 * 4;
#pragma unroll
        for (int i = 0; i < 16; ++i) {
            float4 a = *(const float4*)&As[i][kb];
            acc[i] = fmaf(a.x, wv.x, acc[i]);
            acc[i] = fmaf(a.y, wv.y, acc[i]);
            acc[i] = fmaf(a.z, wv.z, acc[i]);
            acc[i] = fmaf(a.w, wv.w, acc[i]);
        }
    }
    float bv = bias[h];
    int mrows = min(16, M - row0);
    for (int i = 0; i < mrows; ++i)
        C[(size_t)(row0 + i) * H + h] = f2bf(acc[i] + bv);
}

// ---------------- node GEMM: vp = v_in @ W.T (bf16 in/out, fp32 math; Lv_b cancels in BN) ----------------
__global__ __launch_bounds__(256) void k_gemm_node(const u16* __restrict__ A,
                                                   const float* __restrict__ W,
                                                   u16* __restrict__ C) {
    constexpr int TN = 128;
    __shared__ float As[16][TM + 4];
    __shared__ float Bs[16][TN + 4];
    int t = threadIdx.x;
    int row0 = blockIdx.x * TM, col0 = blockIdx.y * TN;
    int rg = t >> 4, cg = t & 15;
    int lar = t >> 2, lak = (t & 3) << 2;
    int lbj = t >> 1, lbk = (t & 1) << 3;
    bool arow = (row0 + lar) < N;
    float acc[4][8];
#pragma unroll
    for (int i = 0; i < 4; ++i)
#pragma unroll
        for (int c = 0; c < 8; ++c) acc[i][c] = 0.f;
    const u16* aptr = A + (size_t)(row0 + lar) * H + lak;
    const float* bptr = W + (size_t)(col0 + lbj) * H + lbk;
    for (int k0 = 0; k0 < H; k0 += 16) {
        ushort4 a4u = arow ? *(const ushort4*)(aptr + k0) : make_ushort4(0, 0, 0, 0);
        float4 b0 = *(const float4*)(bptr + k0);
        float4 b1 = *(const float4*)(bptr + k0 + 4);
        __syncthreads();
        As[lak + 0][lar] = bf2f(a4u.x);
        As[lak + 1][lar] = bf2f(a4u.y);
        As[lak + 2][lar] = bf2f(a4u.z);
        As[lak + 3][lar] = bf2f(a4u.w);
        ST4(Bs, lbk, lbj, b0);
        ST4(Bs, lbk + 4, lbj, b1);
        __syncthreads();
#pragma unroll
        for (int kk = 0; kk < 16; ++kk) {
            float4 av  = *(const float4*)&As[kk][rg << 2];
            float4 bv0 = *(const float4*)&Bs[kk][cg << 3];
            float4 bv1 = *(const float4*)&Bs[kk][(cg << 3) + 4];
            float a_[4] = {av.x, av.y, av.z, av.w};
            float b_[8] = {bv0.x, bv0.y, bv0.z, bv0.w, bv1.x, bv1.y, bv1.z, bv1.w};
#pragma unroll
            for (int c = 0; c < 8; ++c) {
                acc[0][c] = fmaf(a_[0], b_[c], acc[0][c]);
                acc[1][c] = fmaf(a_[1], b_[c], acc[1][c]);
                acc[2][c] = fmaf(a_[2], b_[c], acc[2][c]);
                acc[3][c] = fmaf(a_[3], b_[c], acc[3][c]);
            }
        }
    }
    int rmax = N - row0;
#pragma unroll
    for (int i = 0; i < 4; ++i) {
        int r = (rg << 2) + i;
        if (r < rmax) {
            u16* cp = C + (size_t)(row0 + r) * H + col0 + (cg << 3);
            *(ushort4*)cp       = make_ushort4(f2bf(acc[i][0]), f2bf(acc[i][1]), f2bf(acc[i][2]), f2bf(acc[i][3]));
            *(ushort4*)(cp + 4) = make_ushort4(f2bf(acc[i][4]), f2bf(acc[i][5]), f2bf(acc[i][6]), f2bf(acc[i][7]));
        }
    }
}

// ---------------- MFMA edge pass ----------------
// raw[e][n] = (e_in @ Le_w^T)[e][n] + vp[src_e][n] + vp[dst_e][n]
// FIRST (dst CSR): BN stats (64-slice hierarchical) + raw segmented max into vie.
// !FIRST (src CSR): raw segmented max + e_in += relu(affine(raw)) (tile owns rows).
// MFMA 16x16x32 bf16. A-frag: A[m=lane&15][k=quad*8+j]; B-frag: B[k=quad*8+j][n=lane&15]=W[n][k];
// D: row=quad*4+reg, col=lane&15.  Wave w covers cols n = w*16 + nt*64 + lane16.
template <bool FIRST>
__global__ __launch_bounds__(256, 3) void k_edge_mfma(
    const u16* __restrict__ ein, const u16* __restrict__ wbf,
    const u16* __restrict__ vp, const int* __restrict__ src, const int* __restrict__ dst,
    const int* __restrict__ adj, const int* __restrict__ endo,
    unsigned int* __restrict__ vie, double* __restrict__ stats_e,
    const float* __restrict__ scale, const float* __restrict__ shift,
    u16* __restrict__ ein_rw)
{
    // LDS plan (manual aliasing):
    //  [0,33792)      As[64][264]  (K-loop)  ->  after K-loop:
    //     [0,16896)   Us[64][132]  (u = vp[src]+vp[dst], per column half)
    //     [16896,33536) praw[64][130]
    //  [33792,34304)  s_edge[64]
    //  [34304,34816)  s_node[64]
    //  [34816,35840)  csum[256]
    //  [35840,36864)  csq[256]
    __shared__ char lds[36864];
    u16 (*As)[264]   = (u16(*)[264])lds;
    u16 (*Us)[132]   = (u16(*)[132])lds;
    u16 (*praw)[130] = (u16(*)[130])(lds + 16896);
    int* s_edge = (int*)(lds + 33792);
    int* s_node = (int*)(lds + 34304);
    float* csum = (float*)(lds + 34816);
    float* csq  = (float*)(lds + 35840);

    int t = threadIdx.x;
    int p0 = blockIdx.x * TM;
    if (t < TM) {
        int e = adj[p0 + t];
        s_edge[t] = e;
        int lo = 0, hi = N - 1, p = p0 + t;
        while (lo < hi) { int mid = (lo + hi) >> 1; if (endo[mid] > p) hi = mid; else lo = mid + 1; }
        s_node[t] = lo;
    }
    __syncthreads();
    // stage A tile: 64 rows x 256 K (bf16)
    {
        int r = t >> 2, q = t & 3;
        const u16* gp = ein + (size_t)s_edge[r] * H + q * 64;
#pragma unroll
        for (int i = 0; i < 16; ++i)
            *(ushort4*)&As[r][q * 64 + i * 4] = *(const ushort4*)(gp + i * 4);
    }
    __syncthreads();

    int w = t >> 6, l = t & 63, lane16 = l & 15, quad = l >> 4;
    f32x4 acc[4][4];
#pragma unroll
    for (int i = 0; i < 4; ++i)
#pragma unroll
        for (int j = 0; j < 4; ++j) acc[i][j] = (f32x4){0.f, 0.f, 0.f, 0.f};

    const u16* wb0 = wbf + (size_t)(w * 16 + lane16) * H + quad * 8;
    for (int k0 = 0; k0 < H; k0 += 32) {
        bf16x8 a[4], b[4];
#pragma unroll
        for (int mt = 0; mt < 4; ++mt)
            a[mt] = *(const bf16x8*)&As[mt * 16 + lane16][k0 + quad * 8];
#pragma unroll
        for (int nt = 0; nt < 4; ++nt)
            b[nt] = *(const bf16x8*)(wb0 + (size_t)nt * 64 * H + k0);
#pragma unroll
        for (int mt = 0; mt < 4; ++mt)
#pragma unroll
            for (int nt = 0; nt < 4; ++nt)
                acc[mt][nt] = __builtin_amdgcn_mfma_f32_16x16x32_bf16(a[mt], b[nt], acc[mt][nt], 0, 0, 0);
    }
    __syncthreads();   // As region dead; reuse for Us/praw

#pragma unroll
    for (int half = 0; half < 2; ++half) {
        // stage u for this column half
        {
            int r = t >> 2, q = t & 3;
            int e = s_edge[r];
            const u16* vs = vp + (size_t)src[e] * H + half * 128 + q * 32;
            const u16* vd = vp + (size_t)dst[e] * H + half * 128 + q * 32;
#pragma unroll
            for (int i = 0; i < 8; ++i) {
                ushort4 a4 = *(const ushort4*)(vs + i * 4);
                ushort4 b4 = *(const ushort4*)(vd + i * 4);
                ushort4 o;
                o.x = f2bf(bf2f(a4.x) + bf2f(b4.x));
                o.y = f2bf(bf2f(a4.y) + bf2f(b4.y));
                o.z = f2bf(bf2f(a4.z) + bf2f(b4.z));
                o.w = f2bf(bf2f(a4.w) + bf2f(b4.w));
                *(ushort4*)&Us[r][q * 32 + i * 4] = o;
            }
        }
        __syncthreads();
        // praw = raw (= acc + u) in bf16; BN stats via quad-shuffle reduce
#pragma unroll
        for (int nt2 = 0; nt2 < 2; ++nt2) {
            int cl = w * 16 + nt2 * 64 + lane16;  // local col within half
            float s = 0.f, q2 = 0.f;
#pragma unroll
            for (int mt = 0; mt < 4; ++mt)
#pragma unroll
                for (int reg = 0; reg < 4; ++reg) {
                    int row = mt * 16 + quad * 4 + reg;
                    float v = acc[mt][half * 2 + nt2][reg] + bf2f(Us[row][cl]);
                    praw[row][cl] = f2bf(v);
                    if (FIRST) { s += v; q2 += v * v; }
                }
            if (FIRST) {
                s  += __shfl_xor(s, 16, 64);   s  += __shfl_xor(s, 32, 64);
                q2 += __shfl_xor(q2, 16, 64);  q2 += __shfl_xor(q2, 32, 64);
                if (quad == 0) { csum[half * 128 + cl] = s; csq[half * 128 + cl] = q2; }
            }
        }
        __syncthreads();
        // segmented max walk over node runs (one thread per column)
        if (t < 128) {
            int cl = t, gcol = half * 128 + t;
            int cur = s_node[0];
            float m = bf2f(praw[0][cl]);
            for (int r = 1; r < TM; ++r) {
                int nd = s_node[r];
                float v = bf2f(praw[r][cl]);
                if (nd != cur) {
                    atomicMax(&vie[(size_t)cur * H + gcol], encf(m));
                    cur = nd; m = v;
                } else m = fmaxf(m, v);
            }
            atomicMax(&vie[(size_t)cur * H + gcol], encf(m));
        }
        if (!FIRST) {
            // residual: e_in += relu(affine(raw)), coalesced rows
            int r = t >> 2, q = t & 3;
            u16* gp = ein_rw + (size_t)s_edge[r] * H + half * 128 + q * 32;
            const float* scp = scale + half * 128 + q * 32;
            const float* shp = shift + half * 128 + q * 32;
#pragma unroll
            for (int i = 0; i < 8; ++i) {
                int c = q * 32 + i * 4;
                ushort2 pa = *(const ushort2*)&praw[r][c];
                ushort2 pb = *(const ushort2*)&praw[r][c + 2];
                float4 sc = *(const float4*)(scp + i * 4);
                float4 sh = *(const float4*)(shp + i * 4);
                ushort4 ev = *(const ushort4*)(gp + i * 4);
                float o0 = bf2f(ev.x) + fmaxf(fmaf(bf2f(pa.x), sc.x, sh.x), 0.f);
                float o1 = bf2f(ev.y) + fmaxf(fmaf(bf2f(pa.y), sc.y, sh.y), 0.f);
                float o2 = bf2f(ev.z) + fmaxf(fmaf(bf2f(pb.x), sc.z, sh.z), 0.f);
                float o3 = bf2f(ev.w) + fmaxf(fmaf(bf2f(pb.y), sc.w, sh.w), 0.f);
                *(ushort4*)(gp + i * 4) = make_ushort4(f2bf(o0), f2bf(o1), f2bf(o2), f2bf(o3));
            }
        }
        __syncthreads();
    }
    if (FIRST) {
        int slice = blockIdx.x & 63;
        atomicAdd(&stats_e[(size_t)slice * 512 + t], (double)csum[t]);
        atomicAdd(&stats_e[(size_t)slice * 512 + 256 + t], (double)csq[t]);
    }
}

// ---------------- BN finalize (edge: 64-slice reduce) ----------------
__global__ void k_bn_final_e(const double* __restrict__ stats_e,
                             const float* __restrict__ g, const float* __restrict__ b,
                             float* __restrict__ scale, float* __restrict__ shift) {
    int j = threadIdx.x;
    double m = 0.0, q = 0.0;
    for (int s = 0; s < 64; ++s) {
        m += stats_e[(size_t)s * 512 + j];
        q += stats_e[(size_t)s * 512 + 256 + j];
    }
    m /= (double)E;
    double var = q / (double)E - m * m;
    if (var < 0.0) var = 0.0;
    float inv = rsqrtf((float)var + 1e-5f);
    float sc = g[j] * inv;
    scale[j] = sc;
    shift[j] = b[j] - (float)m * sc;
}

// ---------------- BN finalize (node, single slice) ----------------
__global__ void k_bn_final(const double* __restrict__ stats, int base,
                           const float* __restrict__ g, const float* __restrict__ b,
                           double cnt, float* __restrict__ scale, float* __restrict__ shift) {
    int j = threadIdx.x;
    double m = stats[base + j] / cnt;
    double var = stats[base + 256 + j] / cnt - m * m;
    if (var < 0.0) var = 0.0;
    float inv = rsqrtf((float)var + 1e-5f);
    float sc = g[j] * inv;
    scale[j] = sc;
    shift[j] = b[j] - (float)m * sc;
}

// ---------------- vie finalize: decode raw max, affine+relu; untouched (isolated) -> 0 ----------------
__global__ void k_vie_final(unsigned int* __restrict__ vie_u,
                            const float* __restrict__ scale, const float* __restrict__ shift) {
    size_t idx = ((size_t)blockIdx.x * 256 + threadIdx.x) * 4;
    int col = (int)(idx & (size_t)(H - 1));
    uint4 u = *(const uint4*)(vie_u + idx);
    float4 sc = *(const float4*)(scale + col);
    float4 sh = *(const float4*)(shift + col);
    float4 o;
    o.x = (u.x == 0u) ? 0.f : fmaxf(fmaf(decf(u.x), sc.x, sh.x), 0.f);
    o.y = (u.y == 0u) ? 0.f : fmaxf(fmaf(decf(u.y), sc.y, sh.y), 0.f);
    o.z = (u.z == 0u) ? 0.f : fmaxf(fmaf(decf(u.z), sc.z, sh.z), 0.f);
    o.w = (u.w == 0u) ? 0.f : fmaxf(fmaf(decf(u.w), sc.w, sh.w), 0.f);
    *(float4*)((float*)vie_u + idx) = o;
}

// ---------------- fused GRU: h = (1-z)*n + z*v_in, plus BN stats ----------------
__global__ __launch_bounds__(256) void k_gru(const float* __restrict__ vie, const u16* __restrict__ vin,
                                             const float* __restrict__ wih, const float* __restrict__ whh,
                                             const float* __restrict__ bih, const float* __restrict__ bhh,
                                             u16* __restrict__ hout, double* __restrict__ stats_v) {
    constexpr int TN = 64;
    __shared__ float Ai[16][TM + 4], Ah[16][TM + 4];
    __shared__ float Br[16][TN + 4], Bz[16][TN + 4], Bg[16][TN + 4];
    __shared__ float Cr[16][TN + 4], Cz[16][TN + 4], Cg[16][TN + 4];
    __shared__ float csum[TN], csq[TN];
    int t = threadIdx.x;
    int row0 = blockIdx.x * TM, col0 = blockIdx.y * TN;
    if (t < TN) { csum[t] = 0.f; csq[t] = 0.f; }
    int rg = t >> 4, cg = t & 15;
    int lr = t >> 2, lk = (t & 3) << 2;
    bool arow = (row0 + lr) < N;
    float ar[4][4], az[4][4], ag[4][4], ah[4][4];
#pragma unroll
    for (int i = 0; i < 4; ++i)
#pragma unroll
        for (int c = 0; c < 4; ++c) { ar[i][c] = 0.f; az[i][c] = 0.f; ag[i][c] = 0.f; ah[i][c] = 0.f; }
    const float* aip = vie + (size_t)(row0 + lr) * H + lk;
    const u16* ahp = vin + (size_t)(row0 + lr) * H + lk;
    const float* brp = wih + (size_t)(col0 + lr) * H + lk;
    const float* bzp = wih + (size_t)(256 + col0 + lr) * H + lk;
    const float* bgp = wih + (size_t)(512 + col0 + lr) * H + lk;
    const float* crp = whh + (size_t)(col0 + lr) * H + lk;
    const float* czp = whh + (size_t)(256 + col0 + lr) * H + lk;
    const float* cgp = whh + (size_t)(512 + col0 + lr) * H + lk;
    for (int k0 = 0; k0 < H; k0 += 16) {
        float4 va = arow ? *(const float4*)(aip + k0) : zf4();
        ushort4 vhu = arow ? *(const ushort4*)(ahp + k0) : make_ushort4(0, 0, 0, 0);
        float4 wr = *(const float4*)(brp + k0);
        float4 wz = *(const float4*)(bzp + k0);
        float4 wg = *(const float4*)(bgp + k0);
        float4 ur = *(const float4*)(crp + k0);
        float4 uz = *(const float4*)(czp + k0);
        float4 ug = *(const float4*)(cgp + k0);
        __syncthreads();
        ST4(Ai, lk, lr, va);
        Ah[lk + 0][lr] = bf2f(vhu.x);
        Ah[lk + 1][lr] = bf2f(vhu.y);
        Ah[lk + 2][lr] = bf2f(vhu.z);
        Ah[lk + 3][lr] = bf2f(vhu.w);
        ST4(Br, lk, lr, wr); ST4(Bz, lk, lr, wz); ST4(Bg, lk, lr, wg);
        ST4(Cr, lk, lr, ur); ST4(Cz, lk, lr, uz); ST4(Cg, lk, lr, ug);
        __syncthreads();
#pragma unroll
        for (int kk = 0; kk < 16; ++kk) {
            float4 xa = *(const float4*)&Ai[kk][rg << 2];
            float4 xh = *(const float4*)&Ah[kk][rg << 2];
            float4 r4 = *(const float4*)&Br[kk][cg << 2];
            float4 z4 = *(const float4*)&Bz[kk][cg << 2];
            float4 g4 = *(const float4*)&Bg[kk][cg << 2];
            float4 R4 = *(const float4*)&Cr[kk][cg << 2];
            float4 Z4 = *(const float4*)&Cz[kk][cg << 2];
            float4 G4 = *(const float4*)&Cg[kk][cg << 2];
            float A_[4] = {xa.x, xa.y, xa.z, xa.w};
            float H_[4] = {xh.x, xh.y, xh.z, xh.w};
            float br_[4] = {r4.x, r4.y, r4.z, r4.w}, bz_[4] = {z4.x, z4.y, z4.z, z4.w};
            float bg_[4] = {g4.x, g4.y, g4.z, g4.w};
            float cr_[4] = {R4.x, R4.y, R4.z, R4.w}, cz_[4] = {Z4.x, Z4.y, Z4.z, Z4.w};
            float cg_[4] = {G4.x, G4.y, G4.z, G4.w};
#pragma unroll
            for (int i = 0; i < 4; ++i)
#pragma unroll
                for (int c = 0; c < 4; ++c) {
                    ar[i][c] = fmaf(A_[i], br_[c], fmaf(H_[i], cr_[c], ar[i][c]));
                    az[i][c] = fmaf(A_[i], bz_[c], fmaf(H_[i], cz_[c], az[i][c]));
                    ag[i][c] = fmaf(A_[i], bg_[c], ag[i][c]);
                    ah[i][c] = fmaf(H_[i], cg_[c], ah[i][c]);
                }
        }
    }
    float lsum[4] = {0.f, 0.f, 0.f, 0.f}, lsq[4] = {0.f, 0.f, 0.f, 0.f};
    int rmax = N - row0;
#pragma unroll
    for (int i = 0; i < 4; ++i) {
        int r = (rg << 2) + i;
        bool ok = r < rmax;
        int node = row0 + r;
#pragma unroll
        for (int c = 0; c < 4; ++c) {
            int j = col0 + (cg << 2) + c;
            float rr = sigmf(ar[i][c] + bih[j] + bhh[j]);
            float zz = sigmf(az[i][c] + bih[H + j] + bhh[H + j]);
            float nn = tanhf_(ag[i][c] + bih[2 * H + j] + rr * (ah[i][c] + bhh[2 * H + j]));
            if (ok) {
                float vv = bf2f(vin[(size_t)node * H + j]);
                float hv = (1.f - zz) * nn + zz * vv;
                hout[(size_t)node * H + j] = f2bf(hv);
                lsum[c] += hv; lsq[c] += hv * hv;
            }
        }
    }
#pragma unroll
    for (int c = 0; c < 4; ++c) {
        atomicAdd(&csum[(cg << 2) + c], lsum[c]);
        atomicAdd(&csq[(cg << 2) + c], lsq[c]);
    }
    __syncthreads();
    if (t < TN) {
        atomicAdd(&stats_v[col0 + t], (double)csum[t]);
        atomicAdd(&stats_v[256 + col0 + t], (double)csq[t]);
    }
}

// ---------------- vertex update: v_in += relu(h*scale+shift) (bf16 rmw) ----------------
__global__ void k_vertex_update(u16* __restrict__ vin, const u16* __restrict__ h,
                                const float* __restrict__ scale, const float* __restrict__ shift) {
    size_t idx = ((size_t)blockIdx.x * 256 + threadIdx.x) * 4;
    int col = (int)(idx & (size_t)(H - 1));
    ushort4 hv = *(const ushort4*)(h + idx);
    float4 sc = *(const float4*)(scale + col);
    float4 sh = *(const float4*)(shift + col);
    ushort4 vv = *(const ushort4*)(vin + idx);
    float o0 = bf2f(vv.x) + fmaxf(fmaf(bf2f(hv.x), sc.x, sh.x), 0.f);
    float o1 = bf2f(vv.y) + fmaxf(fmaf(bf2f(hv.y), sc.y, sh.y), 0.f);
    float o2 = bf2f(vv.z) + fmaxf(fmaf(bf2f(hv.z), sc.z, sh.z), 0.f);
    float o3 = bf2f(vv.w) + fmaxf(fmaf(bf2f(hv.w), sc.w, sh.w), 0.f);
    *(ushort4*)(vin + idx) = make_ushort4(f2bf(o0), f2bf(o1), f2bf(o2), f2bf(o3));
}

// ---------------- final: out[e] = e_in[e] . w_fo + b_fo ----------------
__global__ __launch_bounds__(256) void k_final(const u16* __restrict__ ein,
                                               const float* __restrict__ w_fo, float* __restrict__ out) {
    int t = threadIdx.x;
    int lane = t & 63;
    int w = (blockIdx.x << 2) + (t >> 6);
    float4 wv = *(const float4*)(w_fo + lane * 4);
    float bfo = w_fo[H];
    int e0 = w * 64;
    for (int e = e0; e < e0 + 64; ++e) {
        ushort4 u = *(const ushort4*)(ein + (size_t)e * H + lane * 4);
        float p = bf2f(u.x) * wv.x + bf2f(u.y) * wv.y + bf2f(u.z) * wv.z + bf2f(u.w) * wv.w;
        for (int off = 32; off > 0; off >>= 1) p += __shfl_down(p, off, 64);
        if (lane == 0) out[e] = p + bfo;
    }
}

// ---------------- host entry ----------------
extern "C" void kernel_launch(void* const* d_in, const int* in_sizes, int n_in,
                              void* d_out, int out_size, void* d_ws, size_t ws_size,
                              hipStream_t stream) {
    (void)in_sizes; (void)n_in; (void)out_size; (void)ws_size;
    const float* x         = (const float*)d_in[0];
    const float* edge_attr = (const float*)d_in[1];
    const int*   ei        = (const int*)d_in[2];
    const int*   src = ei;
    const int*   dst = ei + E;
    const float* ew  = (const float*)d_in[3];
    const float* eb  = (const float*)d_in[4];
    const float* vw  = (const float*)d_in[5];
    const float* vb  = (const float*)d_in[6];
    const float* Le_w = (const float*)d_in[7];
    // d_in[8] = Le_b : cancels in BN
    const float* Lv_w = (const float*)d_in[9];
    // d_in[10] = Lv_b : cancels in BN
    const float* bne_g = (const float*)d_in[11];
    const float* bne_b = (const float*)d_in[12];
    const float* bnv_g = (const float*)d_in[13];
    const float* bnv_b = (const float*)d_in[14];
    const float* gwih  = (const float*)d_in[15];
    const float* gwhh  = (const float*)d_in[16];
    const float* gbih  = (const float*)d_in[17];
    const float* gbhh  = (const float*)d_in[18];
    const float* fin_w = (const float*)d_in[19];
    const float* fin_b = (const float*)d_in[20];
    const float* out_w = (const float*)d_in[21];
    const float* out_b = (const float*)d_in[22];
    float* out = (float*)d_out;

    const size_t nh = (size_t)N * H, eh = (size_t)E * H;
    char* base = (char*)d_ws;
    size_t off = 0;
    auto alloc = [&](size_t bytes) -> char* {
        char* p = base + off;
        off = (off + bytes + 255) & ~(size_t)255;
        return p;
    };
    float* w_fo = (float*)alloc((H + 1) * sizeof(float));
    u16* v_in = (u16*)alloc(nh * sizeof(u16));
    u16* vp   = (u16*)alloc(nh * sizeof(u16));          // aliased as hbuf after edge passes
    unsigned int* vie_u = (unsigned int*)alloc(nh * sizeof(unsigned int));
    u16* e_in = (u16*)alloc(eh * sizeof(u16));
    u16* wbf  = (u16*)alloc((size_t)NL * H * H * sizeof(u16));
    double* stats_e = (double*)alloc((size_t)64 * 512 * sizeof(double));
    double* stats_v = (double*)alloc(512 * sizeof(double));
    float* scale_e = (float*)alloc(H * sizeof(float));
    float* shift_e = (float*)alloc(H * sizeof(float));
    float* scale_v = (float*)alloc(H * sizeof(float));
    float* shift_v = (float*)alloc(H * sizeof(float));
    int* curS = (int*)alloc((size_t)N * sizeof(int));
    int* curD = (int*)alloc((size_t)N * sizeof(int));
    int* adjS = (int*)alloc((size_t)E * sizeof(int));
    int* adjD = (int*)alloc((size_t)E * sizeof(int));
    u16* hbuf = vp;  // vp dead after edge passes; GRU writes here

    // fused final weights; bf16 edge weights
    k_fuse_final<<<1, 256, 0, stream>>>(fin_w, fin_b, out_w, out_b, w_fo);
    k_cvt_w<<<(NL * H * H / 4 + 255) / 256, 256, 0, stream>>>(Le_w, wbf, NL * H * H / 4);
    // dual CSR
    k_zero_int<<<(N + 255) / 256, 256, 0, stream>>>(curS, N);
    k_zero_int<<<(N + 255) / 256, 256, 0, stream>>>(curD, N);
    k_hist2<<<E / 256, 256, 0, stream>>>(src, dst, curS, curD);
    k_scan<<<1, 256, 0, stream>>>(curS);
    k_scan<<<1, 256, 0, stream>>>(curD);
    k_fill_pair<<<E / 256, 256, 0, stream>>>(src, dst, curS, curD, adjS, adjD);
    // input projections (bf16 out)
    k_in_proj<<<N / 16, 256, 0, stream>>>(x, vw, vb, v_in, N);
    k_in_proj<<<E / 16, 256, 0, stream>>>(edge_attr, ew, eb, e_in, E);

    const int ntile = (N + TM - 1) / TM;
    const int nstat = 64 * 512 + 512;
    for (int k = 0; k < NL; ++k) {
        k_zero_f64<<<(nstat + 255) / 256, 256, 0, stream>>>(stats_e, nstat);  // stats_v contiguous after
        k_fill_u32<<<(int)(nh / 4 / 256), 256, 0, stream>>>(vie_u, 0u);
        k_gemm_node<<<dim3(ntile, 2), 256, 0, stream>>>(v_in, Lv_w + (size_t)k * H * H, vp);
        // dst pass: stats + raw max
        k_edge_mfma<true><<<E / TM, 256, 0, stream>>>(e_in, wbf + (size_t)k * H * H, vp, src, dst,
                                                      adjD, curD, vie_u, stats_e, nullptr, nullptr, nullptr);
        k_bn_final_e<<<1, 256, 0, stream>>>(stats_e, bne_g + k * H, bne_b + k * H, scale_e, shift_e);
        // src pass: raw max + residual into e_in
        k_edge_mfma<false><<<E / TM, 256, 0, stream>>>(e_in, wbf + (size_t)k * H * H, vp, src, dst,
                                                       adjS, curS, vie_u, nullptr, scale_e, shift_e, e_in);
        k_vie_final<<<(int)(nh / 4 / 256), 256, 0, stream>>>(vie_u, scale_e, shift_e);
        k_gru<<<dim3(ntile, 4), 256, 0, stream>>>((const float*)vie_u, v_in,
            gwih + (size_t)k * 3 * H * H, gwhh + (size_t)k * 3 * H * H,
            gbih + (size_t)k * 3 * H, gbhh + (size_t)k * 3 * H, hbuf, stats_v);
        k_bn_final<<<1, 256, 0, stream>>>(stats_v, 0, bnv_g + k * H, bnv_b + k * H, (double)N, scale_v, shift_v);
        k_vertex_update<<<(int)(nh / 4 / 256), 256, 0, stream>>>(v_in, hbuf, scale_v, shift_v);
    }
    k_final<<<E / 256, 256, 0, stream>>>(e_in, w_fo, out);
}

// Round 5
// 3220.693 us; speedup vs baseline: 2.4795x; 1.2301x over previous
//
#include <hip/hip_runtime.h>
#include <stdint.h>

// Problem constants
constexpr int N  = 20000;    // nodes
constexpr int E  = 320000;   // edges
constexpr int H  = 256;      // hidden
constexpr int FEAT = 64;     // FE == FV
constexpr int NL = 4;        // layers
constexpr int FL = 1024;

constexpr int TM = 64;       // GEMM row tile

typedef unsigned short u16;
typedef short bf16x8 __attribute__((ext_vector_type(8)));
typedef float f32x4 __attribute__((ext_vector_type(4)));

// ---------------- bf16 helpers (manual, RNE) ----------------
__device__ __forceinline__ float bf2f(u16 u) {
    union { uint32_t i; float f; } v; v.i = ((uint32_t)u) << 16; return v.f;
}
__device__ __forceinline__ u16 f2bf(float f) {
    union { uint32_t i; float f; } v; v.f = f;
    uint32_t r = v.i + 0x7FFFu + ((v.i >> 16) & 1u);
    return (u16)(r >> 16);
}
__device__ __forceinline__ float sigmf(float x) { return 1.f / (1.f + __expf(-x)); }
__device__ __forceinline__ float tanhf_(float x) { return 2.f / (1.f + __expf(-2.f * x)) - 1.f; }

// order-preserving float<->u32 encoding (for atomic max over signed floats)
__device__ __forceinline__ unsigned int encf(float x) {
    unsigned int u = __float_as_uint(x);
    return (u & 0x80000000u) ? ~u : (u | 0x80000000u);
}
__device__ __forceinline__ float decf(unsigned int k) {
    unsigned int u = (k & 0x80000000u) ? (k ^ 0x80000000u) : ~k;
    return __uint_as_float(u);
}

// B-fragment load: bf16 direct, or fp32 + inline convert (fallback when ws too small)
template <bool W16>
__device__ __forceinline__ bf16x8 ldb(const u16* wb, const float* wf, size_t off) {
    if constexpr (W16) {
        return *(const bf16x8*)(wb + off);
    } else {
        float4 b0 = *(const float4*)(wf + off);
        float4 b1 = *(const float4*)(wf + off + 4);
        bf16x8 r;
        r[0] = (short)f2bf(b0.x); r[1] = (short)f2bf(b0.y);
        r[2] = (short)f2bf(b0.z); r[3] = (short)f2bf(b0.w);
        r[4] = (short)f2bf(b1.x); r[5] = (short)f2bf(b1.y);
        r[6] = (short)f2bf(b1.z); r[7] = (short)f2bf(b1.w);
        return r;
    }
}

// ---------------- K0: fuse fin+out linear layers ----------------
__global__ void k_fuse_final(const float* __restrict__ fin_w, const float* __restrict__ fin_b,
                             const float* __restrict__ out_w, const float* __restrict__ out_b,
                             float* __restrict__ w_fo) {
    int h = threadIdx.x;
    float acc = 0.f;
    for (int f = 0; f < FL; ++f) acc = fmaf(out_w[f], fin_w[(size_t)f * H + h], acc);
    w_fo[h] = acc;
    if (h == 0) {
        float b = 0.f;
        for (int f = 0; f < FL; ++f) b = fmaf(out_w[f], fin_b[f], b);
        w_fo[H] = b + out_b[0];
    }
}

// ---------------- weight convert fp32 -> bf16 ----------------
__global__ void k_cvt_w(const float* __restrict__ w, u16* __restrict__ o, int n4) {
    int i = blockIdx.x * 256 + threadIdx.x;
    if (i < n4) {
        float4 v = *(const float4*)(w + (size_t)i * 4);
        *(ushort4*)(o + (size_t)i * 4) = make_ushort4(f2bf(v.x), f2bf(v.y), f2bf(v.z), f2bf(v.w));
    }
}

// ---------------- CSR build (dual: by src and by dst) ----------------
__global__ void k_zero_int(int* __restrict__ p, int n) {
    int i = blockIdx.x * 256 + threadIdx.x;
    if (i < n) p[i] = 0;
}
__global__ void k_zero_f64(double* __restrict__ p, int n) {
    int i = blockIdx.x * 256 + threadIdx.x;
    if (i < n) p[i] = 0.0;
}
__global__ void k_hist2(const int* __restrict__ src, const int* __restrict__ dst,
                        int* __restrict__ curS, int* __restrict__ curD) {
    int e = blockIdx.x * 256 + threadIdx.x;
    if (e < E) { atomicAdd(&curS[src[e]], 1); atomicAdd(&curD[dst[e]], 1); }
}
__global__ void k_scan(int* __restrict__ cur) {
    __shared__ int cs[256];
    int t = threadIdx.x;
    constexpr int CH = (N + 255) / 256;
    int beg = t * CH, end = min(beg + CH, N);
    int s = 0;
    for (int i = beg; i < end; ++i) s += cur[i];
    cs[t] = s;
    __syncthreads();
    for (int off = 1; off < 256; off <<= 1) {
        int v = cs[t];
        int u = (t >= off) ? cs[t - off] : 0;
        __syncthreads();
        cs[t] = v + u;
        __syncthreads();
    }
    int run = (t > 0) ? cs[t - 1] : 0;
    for (int i = beg; i < end; ++i) { int d = cur[i]; cur[i] = run; run += d; }
}
__global__ void k_fill_pair(const int* __restrict__ src, const int* __restrict__ dst,
                            int* __restrict__ curS, int* __restrict__ curD,
                            int* __restrict__ adjS, int* __restrict__ adjD) {
    int e = blockIdx.x * 256 + threadIdx.x;
    if (e < E) {
        int p = atomicAdd(&curS[src[e]], 1); adjS[p] = e;
        int q = atomicAdd(&curD[dst[e]], 1); adjD[q] = e;
    }
    // after this kernel, curS[v]/curD[v] are END offsets of node v
}
__global__ void k_fill_u32(unsigned int* __restrict__ p, unsigned int val) {
    size_t i = ((size_t)blockIdx.x * 256 + threadIdx.x) * 4;
    uint4 v = make_uint4(val, val, val, val);
    *(uint4*)(p + i) = v;
}

// ---------------- MFMA input projection: C[M,256] = A[M,64] @ W[256,64]^T + b, bf16 out ----------------
template <bool W16>
__global__ __launch_bounds__(256, 3) void k_proj_mfma(
    const float* __restrict__ A, const u16* __restrict__ wb, const float* __restrict__ wf,
    const float* __restrict__ bias, u16* __restrict__ C, int M)
{
    __shared__ u16 As[64][72];
    int t = threadIdx.x;
    int row0 = blockIdx.x * 64;
    int r = t >> 2, q = t & 3;
    if (row0 + r < M) {
        const float* gp = A + (size_t)(row0 + r) * FEAT + q * 16;
#pragma unroll
        for (int i = 0; i < 4; ++i) {
            float4 v = *(const float4*)(gp + i * 4);
            *(ushort4*)&As[r][q * 16 + i * 4] = make_ushort4(f2bf(v.x), f2bf(v.y), f2bf(v.z), f2bf(v.w));
        }
    } else {
#pragma unroll
        for (int i = 0; i < 4; ++i) *(ushort4*)&As[r][q * 16 + i * 4] = make_ushort4(0, 0, 0, 0);
    }
    __syncthreads();
    int w = t >> 6, l = t & 63, lane16 = l & 15, quad = l >> 4;
    f32x4 acc[4][4];
#pragma unroll
    for (int i = 0; i < 4; ++i)
#pragma unroll
        for (int j = 0; j < 4; ++j) acc[i][j] = (f32x4){0.f, 0.f, 0.f, 0.f};
#pragma unroll
    for (int k0 = 0; k0 < FEAT; k0 += 32) {
        bf16x8 a[4], b[4];
#pragma unroll
        for (int mt = 0; mt < 4; ++mt)
            a[mt] = *(const bf16x8*)&As[mt * 16 + lane16][k0 + quad * 8];
#pragma unroll
        for (int nt = 0; nt < 4; ++nt)
            b[nt] = ldb<W16>(wb, wf, (size_t)(w * 16 + nt * 64 + lane16) * FEAT + k0 + quad * 8);
#pragma unroll
        for (int mt = 0; mt < 4; ++mt)
#pragma unroll
            for (int nt = 0; nt < 4; ++nt)
                acc[mt][nt] = __builtin_amdgcn_mfma_f32_16x16x32_bf16(a[mt], b[nt], acc[mt][nt], 0, 0, 0);
    }
#pragma unroll
    for (int nt = 0; nt < 4; ++nt) {
        int col = w * 16 + nt * 64 + lane16;
        float bv = bias[col];
#pragma unroll
        for (int mt = 0; mt < 4; ++mt)
#pragma unroll
            for (int reg = 0; reg < 4; ++reg) {
                int row = mt * 16 + quad * 4 + reg;
                if (row0 + row < M)
                    C[(size_t)(row0 + row) * H + col] = f2bf(acc[mt][nt][reg] + bv);
            }
    }
}

// ---------------- MFMA node GEMM: vp = v_in @ Lv_w^T (Lv_b cancels in BN) ----------------
template <bool W16>
__global__ __launch_bounds__(256, 2) void k_node_mfma(
    const u16* __restrict__ A, const u16* __restrict__ wb, const float* __restrict__ wf,
    u16* __restrict__ C)
{
    __shared__ u16 As[64][264];
    int t = threadIdx.x;
    int row0 = blockIdx.x * 64;
    int rows = min(64, N - row0);
    int r = t >> 2, q = t & 3;
    if (r < rows) {
        const u16* gp = A + (size_t)(row0 + r) * H + q * 64;
#pragma unroll
        for (int i = 0; i < 16; ++i)
            *(ushort4*)&As[r][q * 64 + i * 4] = *(const ushort4*)(gp + i * 4);
    } else {
#pragma unroll
        for (int i = 0; i < 16; ++i) *(ushort4*)&As[r][q * 64 + i * 4] = make_ushort4(0, 0, 0, 0);
    }
    __syncthreads();
    int w = t >> 6, l = t & 63, lane16 = l & 15, quad = l >> 4;
    f32x4 acc[4][4];
#pragma unroll
    for (int i = 0; i < 4; ++i)
#pragma unroll
        for (int j = 0; j < 4; ++j) acc[i][j] = (f32x4){0.f, 0.f, 0.f, 0.f};
    for (int k0 = 0; k0 < H; k0 += 32) {
        bf16x8 a[4], b[4];
#pragma unroll
        for (int mt = 0; mt < 4; ++mt)
            a[mt] = *(const bf16x8*)&As[mt * 16 + lane16][k0 + quad * 8];
#pragma unroll
        for (int nt = 0; nt < 4; ++nt)
            b[nt] = ldb<W16>(wb, wf, (size_t)(w * 16 + nt * 64 + lane16) * H + k0 + quad * 8);
#pragma unroll
        for (int mt = 0; mt < 4; ++mt)
#pragma unroll
            for (int nt = 0; nt < 4; ++nt)
                acc[mt][nt] = __builtin_amdgcn_mfma_f32_16x16x32_bf16(a[mt], b[nt], acc[mt][nt], 0, 0, 0);
    }
#pragma unroll
    for (int nt = 0; nt < 4; ++nt) {
        int col = w * 16 + nt * 64 + lane16;
#pragma unroll
        for (int mt = 0; mt < 4; ++mt)
#pragma unroll
            for (int reg = 0; reg < 4; ++reg) {
                int row = mt * 16 + quad * 4 + reg;
                if (row < rows)
                    C[(size_t)(row0 + row) * H + col] = f2bf(acc[mt][nt][reg]);
            }
    }
}

// ---------------- MFMA edge pass v2 ----------------
// raw[e][n] = (e_in @ Le_w^T)[e][n] + vp[src_e][n] + vp[dst_e][n]
// FIRST (dst CSR): BN stats (64-slice) + raw segmented max into vie.
// !FIRST (src CSR): raw segmented max + e_in += relu(affine(raw)) (tile owns its rows).
template <bool FIRST>
__global__ __launch_bounds__(256, 2) void k_edge_mfma(
    const u16* __restrict__ ein, const u16* __restrict__ wbf,
    const u16* __restrict__ vp, const int* __restrict__ src, const int* __restrict__ dst,
    const int* __restrict__ adj, const int* __restrict__ endo,
    unsigned int* __restrict__ vie, double* __restrict__ stats_e,
    const float* __restrict__ scale, const float* __restrict__ shift,
    u16* __restrict__ ein_rw)
{
    __shared__ u16 As[64][264];      // K-loop A tile; aliased as praw afterwards
    __shared__ u16 Us[64][264];      // vp[src]+vp[dst], staged before K-loop (MFMA hides gather)
    __shared__ int s_edge[64];
    __shared__ int s_node[64];
    __shared__ float csum[256], csq[256];
    u16 (*praw)[264] = As;

    int t = threadIdx.x;
    int p0 = blockIdx.x * TM;
    if (t < TM) {
        int e = adj[p0 + t];
        s_edge[t] = e;
        int lo = 0, hi = N - 1, p = p0 + t;
        while (lo < hi) { int mid = (lo + hi) >> 1; if (endo[mid] > p) hi = mid; else lo = mid + 1; }
        s_node[t] = lo;
    }
    __syncthreads();
    int r = t >> 2, q = t & 3;
    {
        int e = s_edge[r];
        const u16* gp = ein + (size_t)e * H + q * 64;
        const u16* vs = vp + (size_t)src[e] * H + q * 64;
        const u16* vd = vp + (size_t)dst[e] * H + q * 64;
#pragma unroll
        for (int i = 0; i < 16; ++i)
            *(ushort4*)&As[r][q * 64 + i * 4] = *(const ushort4*)(gp + i * 4);
#pragma unroll
        for (int i = 0; i < 16; ++i) {
            ushort4 a4 = *(const ushort4*)(vs + i * 4);
            ushort4 b4 = *(const ushort4*)(vd + i * 4);
            *(ushort4*)&Us[r][q * 64 + i * 4] = make_ushort4(
                f2bf(bf2f(a4.x) + bf2f(b4.x)), f2bf(bf2f(a4.y) + bf2f(b4.y)),
                f2bf(bf2f(a4.z) + bf2f(b4.z)), f2bf(bf2f(a4.w) + bf2f(b4.w)));
        }
    }
    __syncthreads();

    int w = t >> 6, l = t & 63, lane16 = l & 15, quad = l >> 4;
    f32x4 acc[4][4];
#pragma unroll
    for (int i = 0; i < 4; ++i)
#pragma unroll
        for (int j = 0; j < 4; ++j) acc[i][j] = (f32x4){0.f, 0.f, 0.f, 0.f};
    const u16* wb0 = wbf + (size_t)(w * 16 + lane16) * H + quad * 8;
    for (int k0 = 0; k0 < H; k0 += 32) {
        bf16x8 a[4], b[4];
#pragma unroll
        for (int mt = 0; mt < 4; ++mt)
            a[mt] = *(const bf16x8*)&As[mt * 16 + lane16][k0 + quad * 8];
#pragma unroll
        for (int nt = 0; nt < 4; ++nt)
            b[nt] = *(const bf16x8*)(wb0 + (size_t)nt * 64 * H + k0);
#pragma unroll
        for (int mt = 0; mt < 4; ++mt)
#pragma unroll
            for (int nt = 0; nt < 4; ++nt)
                acc[mt][nt] = __builtin_amdgcn_mfma_f32_16x16x32_bf16(a[mt], b[nt], acc[mt][nt], 0, 0, 0);
    }
    __syncthreads();   // As reads complete -> region becomes praw

#pragma unroll
    for (int nt = 0; nt < 4; ++nt) {
        int col = w * 16 + nt * 64 + lane16;
        float s = 0.f, qq = 0.f;
#pragma unroll
        for (int mt = 0; mt < 4; ++mt)
#pragma unroll
            for (int reg = 0; reg < 4; ++reg) {
                int row = mt * 16 + quad * 4 + reg;
                float v = acc[mt][nt][reg] + bf2f(Us[row][col]);
                praw[row][col] = f2bf(v);
                if (FIRST) { s += v; qq += v * v; }
            }
        if (FIRST) {
            s  += __shfl_xor(s, 16, 64);  s  += __shfl_xor(s, 32, 64);
            qq += __shfl_xor(qq, 16, 64); qq += __shfl_xor(qq, 32, 64);
            if (quad == 0) { csum[col] = s; csq[col] = qq; }
        }
    }
    __syncthreads();
    // segmented max walk over node runs: thread t owns column t
    {
        int cur = s_node[0];
        float m = bf2f(praw[0][t]);
        for (int rr = 1; rr < TM; ++rr) {
            int nd = s_node[rr];
            float v = bf2f(praw[rr][t]);
            if (nd != cur) {
                atomicMax(&vie[(size_t)cur * H + t], encf(m));
                cur = nd; m = v;
            } else m = fmaxf(m, v);
        }
        atomicMax(&vie[(size_t)cur * H + t], encf(m));
    }
    if (FIRST) {
        int slice = blockIdx.x & 63;
        atomicAdd(&stats_e[(size_t)slice * 512 + t], (double)csum[t]);
        atomicAdd(&stats_e[(size_t)slice * 512 + 256 + t], (double)csq[t]);
    } else {
        u16* gp = ein_rw + (size_t)s_edge[r] * H + q * 64;
        const float* scp = scale + q * 64;
        const float* shp = shift + q * 64;
#pragma unroll
        for (int i = 0; i < 16; ++i) {
            int c = q * 64 + i * 4;
            ushort2 pa = *(const ushort2*)&praw[r][c];
            ushort2 pb = *(const ushort2*)&praw[r][c + 2];
            float4 sc = *(const float4*)(scp + i * 4);
            float4 sh = *(const float4*)(shp + i * 4);
            ushort4 ev = *(const ushort4*)(gp + i * 4);
            float o0 = bf2f(ev.x) + fmaxf(fmaf(bf2f(pa.x), sc.x, sh.x), 0.f);
            float o1 = bf2f(ev.y) + fmaxf(fmaf(bf2f(pa.y), sc.y, sh.y), 0.f);
            float o2 = bf2f(ev.z) + fmaxf(fmaf(bf2f(pb.x), sc.z, sh.z), 0.f);
            float o3 = bf2f(ev.w) + fmaxf(fmaf(bf2f(pb.y), sc.w, sh.w), 0.f);
            *(ushort4*)(gp + i * 4) = make_ushort4(f2bf(o0), f2bf(o1), f2bf(o2), f2bf(o3));
        }
    }
}

// ---------------- BN finalize (edge: 64-slice reduce) ----------------
__global__ void k_bn_final_e(const double* __restrict__ stats_e,
                             const float* __restrict__ g, const float* __restrict__ b,
                             float* __restrict__ scale, float* __restrict__ shift) {
    int j = threadIdx.x;
    double m = 0.0, q = 0.0;
    for (int s = 0; s < 64; ++s) {
        m += stats_e[(size_t)s * 512 + j];
        q += stats_e[(size_t)s * 512 + 256 + j];
    }
    m /= (double)E;
    double var = q / (double)E - m * m;
    if (var < 0.0) var = 0.0;
    float inv = rsqrtf((float)var + 1e-5f);
    float sc = g[j] * inv;
    scale[j] = sc;
    shift[j] = b[j] - (float)m * sc;
}

// ---------------- BN finalize (node, single slice) ----------------
__global__ void k_bn_final(const double* __restrict__ stats, int base,
                           const float* __restrict__ g, const float* __restrict__ b,
                           double cnt, float* __restrict__ scale, float* __restrict__ shift) {
    int j = threadIdx.x;
    double m = stats[base + j] / cnt;
    double var = stats[base + 256 + j] / cnt - m * m;
    if (var < 0.0) var = 0.0;
    float inv = rsqrtf((float)var + 1e-5f);
    float sc = g[j] * inv;
    scale[j] = sc;
    shift[j] = b[j] - (float)m * sc;
}

// ---------------- vie finalize: decode raw max, affine+relu; untouched (isolated) -> 0 ----------------
__global__ void k_vie_final(unsigned int* __restrict__ vie_u,
                            const float* __restrict__ scale, const float* __restrict__ shift) {
    size_t idx = ((size_t)blockIdx.x * 256 + threadIdx.x) * 4;
    int col = (int)(idx & (size_t)(H - 1));
    uint4 u = *(const uint4*)(vie_u + idx);
    float4 sc = *(const float4*)(scale + col);
    float4 sh = *(const float4*)(shift + col);
    float4 o;
    o.x = (u.x == 0u) ? 0.f : fmaxf(fmaf(decf(u.x), sc.x, sh.x), 0.f);
    o.y = (u.y == 0u) ? 0.f : fmaxf(fmaf(decf(u.y), sc.y, sh.y), 0.f);
    o.z = (u.z == 0u) ? 0.f : fmaxf(fmaf(decf(u.z), sc.z, sh.z), 0.f);
    o.w = (u.w == 0u) ? 0.f : fmaxf(fmaf(decf(u.w), sc.w, sh.w), 0.f);
    *(float4*)((float*)vie_u + idx) = o;
}

// ---------------- MFMA fused GRU: h = (1-z)*n + z*v_in, plus BN stats ----------------
// accR = vie@Wih_r^T + vin@Whh_r^T (combined), same for Z; IG/HG kept separate (r gates hg).
template <bool W16>
__global__ __launch_bounds__(256, 2) void k_gru_mfma(
    const float* __restrict__ vie, const u16* __restrict__ vin,
    const u16* __restrict__ wihb, const float* __restrict__ wihf,
    const u16* __restrict__ whhb, const float* __restrict__ whhf,
    const float* __restrict__ bih, const float* __restrict__ bhh,
    u16* __restrict__ hout, double* __restrict__ stats_v)
{
    __shared__ u16 Ae[64][264];   // vie (bf16-staged)
    __shared__ u16 Av[64][264];   // vin
    __shared__ float csum[256], csq[256];
    int t = threadIdx.x;
    int row0 = blockIdx.x * 64;
    int rows = min(64, N - row0);
    int r = t >> 2, q = t & 3;
    if (r < rows) {
        const float* gp = vie + (size_t)(row0 + r) * H + q * 64;
        const u16* hp = vin + (size_t)(row0 + r) * H + q * 64;
#pragma unroll
        for (int i = 0; i < 16; ++i) {
            float4 v = *(const float4*)(gp + i * 4);
            *(ushort4*)&Ae[r][q * 64 + i * 4] = make_ushort4(f2bf(v.x), f2bf(v.y), f2bf(v.z), f2bf(v.w));
            *(ushort4*)&Av[r][q * 64 + i * 4] = *(const ushort4*)(hp + i * 4);
        }
    } else {
#pragma unroll
        for (int i = 0; i < 16; ++i) {
            *(ushort4*)&Ae[r][q * 64 + i * 4] = make_ushort4(0, 0, 0, 0);
            *(ushort4*)&Av[r][q * 64 + i * 4] = make_ushort4(0, 0, 0, 0);
        }
    }
    __syncthreads();
    int w = t >> 6, l = t & 63, lane16 = l & 15, quad = l >> 4;

    for (int g = 0; g < 4; ++g) {
        int j = g * 64 + w * 16 + lane16;
        f32x4 aR[4], aZ[4], aIG[4], aHG[4];
#pragma unroll
        for (int mt = 0; mt < 4; ++mt) {
            aR[mt] = (f32x4){0.f, 0.f, 0.f, 0.f};  aZ[mt] = (f32x4){0.f, 0.f, 0.f, 0.f};
            aIG[mt] = (f32x4){0.f, 0.f, 0.f, 0.f}; aHG[mt] = (f32x4){0.f, 0.f, 0.f, 0.f};
        }
        for (int k0 = 0; k0 < H; k0 += 32) {
            size_t kq = (size_t)k0 + quad * 8;
            bf16x8 ae[4], av[4];
#pragma unroll
            for (int mt = 0; mt < 4; ++mt) {
                ae[mt] = *(const bf16x8*)&Ae[mt * 16 + lane16][k0 + quad * 8];
                av[mt] = *(const bf16x8*)&Av[mt * 16 + lane16][k0 + quad * 8];
            }
            bf16x8 bri = ldb<W16>(wihb, wihf, (size_t)j * H + kq);
            bf16x8 bzi = ldb<W16>(wihb, wihf, (size_t)(H + j) * H + kq);
            bf16x8 bgi = ldb<W16>(wihb, wihf, (size_t)(2 * H + j) * H + kq);
            bf16x8 brh = ldb<W16>(whhb, whhf, (size_t)j * H + kq);
            bf16x8 bzh = ldb<W16>(whhb, whhf, (size_t)(H + j) * H + kq);
            bf16x8 bgh = ldb<W16>(whhb, whhf, (size_t)(2 * H + j) * H + kq);
#pragma unroll
            for (int mt = 0; mt < 4; ++mt) {
                aR[mt]  = __builtin_amdgcn_mfma_f32_16x16x32_bf16(ae[mt], bri, aR[mt], 0, 0, 0);
                aR[mt]  = __builtin_amdgcn_mfma_f32_16x16x32_bf16(av[mt], brh, aR[mt], 0, 0, 0);
                aZ[mt]  = __builtin_amdgcn_mfma_f32_16x16x32_bf16(ae[mt], bzi, aZ[mt], 0, 0, 0);
                aZ[mt]  = __builtin_amdgcn_mfma_f32_16x16x32_bf16(av[mt], bzh, aZ[mt], 0, 0, 0);
                aIG[mt] = __builtin_amdgcn_mfma_f32_16x16x32_bf16(ae[mt], bgi, aIG[mt], 0, 0, 0);
                aHG[mt] = __builtin_amdgcn_mfma_f32_16x16x32_bf16(av[mt], bgh, aHG[mt], 0, 0, 0);
            }
        }
        float br_ = bih[j] + bhh[j];
        float bz_ = bih[H + j] + bhh[H + j];
        float bgi_ = bih[2 * H + j];
        float bgh_ = bhh[2 * H + j];
        float s = 0.f, qq = 0.f;
#pragma unroll
        for (int mt = 0; mt < 4; ++mt)
#pragma unroll
            for (int reg = 0; reg < 4; ++reg) {
                int row = mt * 16 + quad * 4 + reg;
                float rr = sigmf(aR[mt][reg] + br_);
                float zz = sigmf(aZ[mt][reg] + bz_);
                float nn = tanhf_(aIG[mt][reg] + bgi_ + rr * (aHG[mt][reg] + bgh_));
                float vv = bf2f(Av[row][j]);
                float hv = (1.f - zz) * nn + zz * vv;
                if (row < rows) {
                    hout[(size_t)(row0 + row) * H + j] = f2bf(hv);
                    s += hv; qq += hv * hv;
                }
            }
        s  += __shfl_xor(s, 16, 64);  s  += __shfl_xor(s, 32, 64);
        qq += __shfl_xor(qq, 16, 64); qq += __shfl_xor(qq, 32, 64);
        if (quad == 0) { csum[j] = s; csq[j] = qq; }
    }
    __syncthreads();
    atomicAdd(&stats_v[t], (double)csum[t]);
    atomicAdd(&stats_v[256 + t], (double)csq[t]);
}

// ---------------- vertex update: v_in += relu(h*scale+shift) (bf16 rmw) ----------------
__global__ void k_vertex_update(u16* __restrict__ vin, const u16* __restrict__ h,
                                const float* __restrict__ scale, const float* __restrict__ shift) {
    size_t idx = ((size_t)blockIdx.x * 256 + threadIdx.x) * 4;
    int col = (int)(idx & (size_t)(H - 1));
    ushort4 hv = *(const ushort4*)(h + idx);
    float4 sc = *(const float4*)(scale + col);
    float4 sh = *(const float4*)(shift + col);
    ushort4 vv = *(const ushort4*)(vin + idx);
    float o0 = bf2f(vv.x) + fmaxf(fmaf(bf2f(hv.x), sc.x, sh.x), 0.f);
    float o1 = bf2f(vv.y) + fmaxf(fmaf(bf2f(hv.y), sc.y, sh.y), 0.f);
    float o2 = bf2f(vv.z) + fmaxf(fmaf(bf2f(hv.z), sc.z, sh.z), 0.f);
    float o3 = bf2f(vv.w) + fmaxf(fmaf(bf2f(hv.w), sc.w, sh.w), 0.f);
    *(ushort4*)(vin + idx) = make_ushort4(f2bf(o0), f2bf(o1), f2bf(o2), f2bf(o3));
}

// ---------------- final: out[e] = e_in[e] . w_fo + b_fo ----------------
__global__ __launch_bounds__(256) void k_final(const u16* __restrict__ ein,
                                               const float* __restrict__ w_fo, float* __restrict__ out) {
    int t = threadIdx.x;
    int lane = t & 63;
    int w = (blockIdx.x << 2) + (t >> 6);
    float4 wv = *(const float4*)(w_fo + lane * 4);
    float bfo = w_fo[H];
    int e0 = w * 64;
    for (int e = e0; e < e0 + 64; ++e) {
        ushort4 u = *(const ushort4*)(ein + (size_t)e * H + lane * 4);
        float p = bf2f(u.x) * wv.x + bf2f(u.y) * wv.y + bf2f(u.z) * wv.z + bf2f(u.w) * wv.w;
        for (int off = 32; off > 0; off >>= 1) p += __shfl_down(p, off, 64);
        if (lane == 0) out[e] = p + bfo;
    }
}

// ---------------- pipeline ----------------
template <bool W16>
static void run_all(void* const* d_in, void* d_out, void* d_ws, hipStream_t stream) {
    const float* x         = (const float*)d_in[0];
    const float* edge_attr = (const float*)d_in[1];
    const int*   ei        = (const int*)d_in[2];
    const int*   src = ei;
    const int*   dst = ei + E;
    const float* ew  = (const float*)d_in[3];
    const float* eb  = (const float*)d_in[4];
    const float* vw  = (const float*)d_in[5];
    const float* vb  = (const float*)d_in[6];
    const float* Le_w = (const float*)d_in[7];
    // d_in[8] = Le_b : cancels in BN
    const float* Lv_w = (const float*)d_in[9];
    // d_in[10] = Lv_b : cancels in BN
    const float* bne_g = (const float*)d_in[11];
    const float* bne_b = (const float*)d_in[12];
    const float* bnv_g = (const float*)d_in[13];
    const float* bnv_b = (const float*)d_in[14];
    const float* gwih  = (const float*)d_in[15];
    const float* gwhh  = (const float*)d_in[16];
    const float* gbih  = (const float*)d_in[17];
    const float* gbhh  = (const float*)d_in[18];
    const float* fin_w = (const float*)d_in[19];
    const float* fin_b = (const float*)d_in[20];
    const float* out_w = (const float*)d_in[21];
    const float* out_b = (const float*)d_in[22];
    float* out = (float*)d_out;

    const size_t nh = (size_t)N * H, eh = (size_t)E * H;
    char* base = (char*)d_ws;
    size_t off = 0;
    auto alloc = [&](size_t bytes) -> char* {
        char* p = base + off;
        off = (off + bytes + 255) & ~(size_t)255;
        return p;
    };
    float* w_fo = (float*)alloc((H + 1) * sizeof(float));
    u16* v_in = (u16*)alloc(nh * sizeof(u16));
    u16* vp   = (u16*)alloc(nh * sizeof(u16));          // aliased as hbuf after edge passes
    unsigned int* vie_u = (unsigned int*)alloc(nh * sizeof(unsigned int));
    u16* e_in = (u16*)alloc(eh * sizeof(u16));
    u16* wbf  = (u16*)alloc((size_t)NL * H * H * sizeof(u16));   // Le_w bf16 (always)
    double* stats_e = (double*)alloc((size_t)64 * 512 * sizeof(double));
    double* stats_v = (double*)alloc(512 * sizeof(double));
    float* scale_e = (float*)alloc(H * sizeof(float));
    float* shift_e = (float*)alloc(H * sizeof(float));
    float* scale_v = (float*)alloc(H * sizeof(float));
    float* shift_v = (float*)alloc(H * sizeof(float));
    int* curS = (int*)alloc((size_t)N * sizeof(int));
    int* curD = (int*)alloc((size_t)N * sizeof(int));
    int* adjS = (int*)alloc((size_t)E * sizeof(int));
    int* adjD = (int*)alloc((size_t)E * sizeof(int));
    // optional bf16 weight copies (only consumed when W16)
    u16 *wbf_v = nullptr, *wbf_ih = nullptr, *wbf_hh = nullptr, *ew_b = nullptr, *vw_b = nullptr;
    if (W16) {
        wbf_v  = (u16*)alloc((size_t)NL * H * H * sizeof(u16));
        wbf_ih = (u16*)alloc((size_t)NL * 3 * H * H * sizeof(u16));
        wbf_hh = (u16*)alloc((size_t)NL * 3 * H * H * sizeof(u16));
        ew_b   = (u16*)alloc((size_t)H * FEAT * sizeof(u16));
        vw_b   = (u16*)alloc((size_t)H * FEAT * sizeof(u16));
    }
    u16* hbuf = vp;  // vp dead after edge passes; GRU writes here

    // fused final weights; bf16 weight conversions
    k_fuse_final<<<1, 256, 0, stream>>>(fin_w, fin_b, out_w, out_b, w_fo);
    k_cvt_w<<<(NL * H * H / 4 + 255) / 256, 256, 0, stream>>>(Le_w, wbf, NL * H * H / 4);
    if (W16) {
        k_cvt_w<<<(NL * H * H / 4 + 255) / 256, 256, 0, stream>>>(Lv_w, wbf_v, NL * H * H / 4);
        k_cvt_w<<<(NL * 3 * H * H / 4 + 255) / 256, 256, 0, stream>>>(gwih, wbf_ih, NL * 3 * H * H / 4);
        k_cvt_w<<<(NL * 3 * H * H / 4 + 255) / 256, 256, 0, stream>>>(gwhh, wbf_hh, NL * 3 * H * H / 4);
        k_cvt_w<<<(H * FEAT / 4 + 255) / 256, 256, 0, stream>>>(ew, ew_b, H * FEAT / 4);
        k_cvt_w<<<(H * FEAT / 4 + 255) / 256, 256, 0, stream>>>(vw, vw_b, H * FEAT / 4);
    }
    // dual CSR
    k_zero_int<<<(N + 255) / 256, 256, 0, stream>>>(curS, N);
    k_zero_int<<<(N + 255) / 256, 256, 0, stream>>>(curD, N);
    k_hist2<<<E / 256, 256, 0, stream>>>(src, dst, curS, curD);
    k_scan<<<1, 256, 0, stream>>>(curS);
    k_scan<<<1, 256, 0, stream>>>(curD);
    k_fill_pair<<<E / 256, 256, 0, stream>>>(src, dst, curS, curD, adjS, adjD);
    // input projections (MFMA, bf16 out)
    const int ntile = (N + 63) / 64;
    k_proj_mfma<W16><<<ntile, 256, 0, stream>>>(x, vw_b, vw, vb, v_in, N);
    k_proj_mfma<W16><<<E / 64, 256, 0, stream>>>(edge_attr, ew_b, ew, eb, e_in, E);

    const int nstat = 64 * 512 + 512;
    for (int k = 0; k < NL; ++k) {
        k_zero_f64<<<(nstat + 255) / 256, 256, 0, stream>>>(stats_e, nstat);  // stats_v contiguous after
        k_fill_u32<<<(int)(nh / 4 / 256), 256, 0, stream>>>(vie_u, 0u);
        k_node_mfma<W16><<<ntile, 256, 0, stream>>>(v_in,
            W16 ? wbf_v + (size_t)k * H * H : nullptr, Lv_w + (size_t)k * H * H, vp);
        // dst pass: stats + raw max
        k_edge_mfma<true><<<E / TM, 256, 0, stream>>>(e_in, wbf + (size_t)k * H * H, vp, src, dst,
                                                      adjD, curD, vie_u, stats_e, nullptr, nullptr, nullptr);
        k_bn_final_e<<<1, 256, 0, stream>>>(stats_e, bne_g + k * H, bne_b + k * H, scale_e, shift_e);
        // src pass: raw max + residual into e_in
        k_edge_mfma<false><<<E / TM, 256, 0, stream>>>(e_in, wbf + (size_t)k * H * H, vp, src, dst,
                                                       adjS, curS, vie_u, nullptr, scale_e, shift_e, e_in);
        k_vie_final<<<(int)(nh / 4 / 256), 256, 0, stream>>>(vie_u, scale_e, shift_e);
        k_gru_mfma<W16><<<ntile, 256, 0, stream>>>((const float*)vie_u, v_in,
            W16 ? wbf_ih + (size_t)k * 3 * H * H : nullptr, gwih + (size_t)k * 3 * H * H,
            W16 ? wbf_hh + (size_t)k * 3 * H * H : nullptr, gwhh + (size_t)k * 3 * H * H,
            gbih + (size_t)k * 3 * H, gbhh + (size_t)k * 3 * H, hbuf, stats_v);
        k_bn_final<<<1, 256, 0, stream>>>(stats_v, 0, bnv_g + k * H, bnv_b + k * H, (double)N, scale_v, shift_v);
        k_vertex_update<<<(int)(nh / 4 / 256), 256, 0, stream>>>(v_in, hbuf, scale_v, shift_v);
    }
    k_final<<<E / 256, 256, 0, stream>>>(e_in, w_fo, out);
}

// ---------------- host entry ----------------
extern "C" void kernel_launch(void* const* d_in, const int* in_sizes, int n_in,
                              void* d_out, int out_size, void* d_ws, size_t ws_size,
                              hipStream_t stream) {
    (void)in_sizes; (void)n_in; (void)out_size;
    const size_t nh = (size_t)N * H, eh = (size_t)E * H;
    auto rup = [](size_t x) { return (x + 255) & ~(size_t)255; };
    size_t need_base = rup((H + 1) * 4) + 2 * rup(nh * 2) + rup(nh * 4) + rup(eh * 2)
                     + rup((size_t)NL * H * H * 2) + rup((size_t)64 * 512 * 8) + rup(512 * 8)
                     + 4 * rup(H * 4) + 2 * rup((size_t)N * 4) + 2 * rup((size_t)E * 4);
    size_t need_full = need_base + rup((size_t)NL * H * H * 2)
                     + 2 * rup((size_t)NL * 3 * H * H * 2) + 2 * rup((size_t)H * FEAT * 2);
    if (ws_size == 0 || ws_size >= need_full)
        run_all<true>(d_in, d_out, d_ws, stream);   // bf16 weight copies fit
    else
        run_all<false>(d_in, d_out, d_ws, stream);  // inline fp32->bf16 B-fragment converts
}

// Round 6
// 3214.417 us; speedup vs baseline: 2.4844x; 1.0020x over previous
//
#include <hip/hip_runtime.h>
#include <stdint.h>

// Problem constants
constexpr int N  = 20000;    // nodes
constexpr int E  = 320000;   // edges
constexpr int H  = 256;      // hidden
constexpr int FEAT = 64;     // FE == FV
constexpr int NL = 4;        // layers
constexpr int FL = 1024;

typedef unsigned short u16;
typedef short bf16x8 __attribute__((ext_vector_type(8)));
typedef float f32x4 __attribute__((ext_vector_type(4)));

// ---------------- bf16 helpers (manual, RNE) ----------------
__device__ __forceinline__ float bf2f(u16 u) {
    union { uint32_t i; float f; } v; v.i = ((uint32_t)u) << 16; return v.f;
}
__device__ __forceinline__ u16 f2bf(float f) {
    union { uint32_t i; float f; } v; v.f = f;
    uint32_t r = v.i + 0x7FFFu + ((v.i >> 16) & 1u);
    return (u16)(r >> 16);
}
__device__ __forceinline__ float sigmf(float x) { return 1.f / (1.f + __expf(-x)); }
__device__ __forceinline__ float tanhf_(float x) { return 2.f / (1.f + __expf(-2.f * x)) - 1.f; }

// order-preserving float<->u32 encoding (for atomic max over signed floats)
__device__ __forceinline__ unsigned int encf(float x) {
    unsigned int u = __float_as_uint(x);
    return (u & 0x80000000u) ? ~u : (u | 0x80000000u);
}
__device__ __forceinline__ float decf(unsigned int k) {
    unsigned int u = (k & 0x80000000u) ? (k ^ 0x80000000u) : ~k;
    return __uint_as_float(u);
}

// B-fragment load: bf16 direct, or fp32 + inline convert (fallback when ws too small)
template <bool W16>
__device__ __forceinline__ bf16x8 ldb(const u16* wb, const float* wf, size_t off) {
    if constexpr (W16) {
        return *(const bf16x8*)(wb + off);
    } else {
        float4 b0 = *(const float4*)(wf + off);
        float4 b1 = *(const float4*)(wf + off + 4);
        bf16x8 r;
        r[0] = (short)f2bf(b0.x); r[1] = (short)f2bf(b0.y);
        r[2] = (short)f2bf(b0.z); r[3] = (short)f2bf(b0.w);
        r[4] = (short)f2bf(b1.x); r[5] = (short)f2bf(b1.y);
        r[6] = (short)f2bf(b1.z); r[7] = (short)f2bf(b1.w);
        return r;
    }
}

// ---------------- K0: fuse fin+out linear layers ----------------
__global__ void k_fuse_final(const float* __restrict__ fin_w, const float* __restrict__ fin_b,
                             const float* __restrict__ out_w, const float* __restrict__ out_b,
                             float* __restrict__ w_fo) {
    int h = threadIdx.x;
    float acc = 0.f;
    for (int f = 0; f < FL; ++f) acc = fmaf(out_w[f], fin_w[(size_t)f * H + h], acc);
    w_fo[h] = acc;
    if (h == 0) {
        float b = 0.f;
        for (int f = 0; f < FL; ++f) b = fmaf(out_w[f], fin_b[f], b);
        w_fo[H] = b + out_b[0];
    }
}

// ---------------- weight convert fp32 -> bf16 ----------------
__global__ void k_cvt_w(const float* __restrict__ w, u16* __restrict__ o, int n4) {
    int i = blockIdx.x * 256 + threadIdx.x;
    if (i < n4) {
        float4 v = *(const float4*)(w + (size_t)i * 4);
        *(ushort4*)(o + (size_t)i * 4) = make_ushort4(f2bf(v.x), f2bf(v.y), f2bf(v.z), f2bf(v.w));
    }
}

// ---------------- CSR build (dual: by src and by dst) ----------------
__global__ void k_zero_int(int* __restrict__ p, int n) {
    int i = blockIdx.x * 256 + threadIdx.x;
    if (i < n) p[i] = 0;
}
__global__ void k_zero_f64(double* __restrict__ p, int n) {
    int i = blockIdx.x * 256 + threadIdx.x;
    if (i < n) p[i] = 0.0;
}
__global__ void k_hist2(const int* __restrict__ src, const int* __restrict__ dst,
                        int* __restrict__ curS, int* __restrict__ curD) {
    int e = blockIdx.x * 256 + threadIdx.x;
    if (e < E) { atomicAdd(&curS[src[e]], 1); atomicAdd(&curD[dst[e]], 1); }
}
__global__ void k_scan(int* __restrict__ cur) {
    __shared__ int cs[256];
    int t = threadIdx.x;
    constexpr int CH = (N + 255) / 256;
    int beg = t * CH, end = min(beg + CH, N);
    int s = 0;
    for (int i = beg; i < end; ++i) s += cur[i];
    cs[t] = s;
    __syncthreads();
    for (int off = 1; off < 256; off <<= 1) {
        int v = cs[t];
        int u = (t >= off) ? cs[t - off] : 0;
        __syncthreads();
        cs[t] = v + u;
        __syncthreads();
    }
    int run = (t > 0) ? cs[t - 1] : 0;
    for (int i = beg; i < end; ++i) { int d = cur[i]; cur[i] = run; run += d; }
}
__global__ void k_fill_pair(const int* __restrict__ src, const int* __restrict__ dst,
                            int* __restrict__ curS, int* __restrict__ curD,
                            int* __restrict__ adjS, int* __restrict__ adjD) {
    int e = blockIdx.x * 256 + threadIdx.x;
    if (e < E) {
        int p = atomicAdd(&curS[src[e]], 1); adjS[p] = e;
        int q = atomicAdd(&curD[dst[e]], 1); adjD[q] = e;
    }
    // after this kernel, curS[v]/curD[v] are END offsets of node v
}
__global__ void k_fill_u32(unsigned int* __restrict__ p, unsigned int val) {
    size_t i = ((size_t)blockIdx.x * 256 + threadIdx.x) * 4;
    uint4 v = make_uint4(val, val, val, val);
    *(uint4*)(p + i) = v;
}

// ---------------- MFMA input projection: C[M,256] = A[M,64] @ W[256,64]^T + b, bf16 out ----------------
template <bool W16>
__global__ __launch_bounds__(256, 3) void k_proj_mfma(
    const float* __restrict__ A, const u16* __restrict__ wb, const float* __restrict__ wf,
    const float* __restrict__ bias, u16* __restrict__ C, int M)
{
    __shared__ u16 As[64][72];
    int t = threadIdx.x;
    int row0 = blockIdx.x * 64;
    int r = t >> 2, q = t & 3;
    if (row0 + r < M) {
        const float* gp = A + (size_t)(row0 + r) * FEAT + q * 16;
#pragma unroll
        for (int i = 0; i < 4; ++i) {
            float4 v = *(const float4*)(gp + i * 4);
            *(ushort4*)&As[r][q * 16 + i * 4] = make_ushort4(f2bf(v.x), f2bf(v.y), f2bf(v.z), f2bf(v.w));
        }
    } else {
#pragma unroll
        for (int i = 0; i < 4; ++i) *(ushort4*)&As[r][q * 16 + i * 4] = make_ushort4(0, 0, 0, 0);
    }
    __syncthreads();
    int w = t >> 6, l = t & 63, lane16 = l & 15, quad = l >> 4;
    f32x4 acc[4][4];
#pragma unroll
    for (int i = 0; i < 4; ++i)
#pragma unroll
        for (int j = 0; j < 4; ++j) acc[i][j] = (f32x4){0.f, 0.f, 0.f, 0.f};
#pragma unroll
    for (int k0 = 0; k0 < FEAT; k0 += 32) {
        bf16x8 a[4], b[4];
#pragma unroll
        for (int mt = 0; mt < 4; ++mt)
            a[mt] = *(const bf16x8*)&As[mt * 16 + lane16][k0 + quad * 8];
#pragma unroll
        for (int nt = 0; nt < 4; ++nt)
            b[nt] = ldb<W16>(wb, wf, (size_t)(w * 16 + nt * 64 + lane16) * FEAT + k0 + quad * 8);
#pragma unroll
        for (int mt = 0; mt < 4; ++mt)
#pragma unroll
            for (int nt = 0; nt < 4; ++nt)
                acc[mt][nt] = __builtin_amdgcn_mfma_f32_16x16x32_bf16(a[mt], b[nt], acc[mt][nt], 0, 0, 0);
    }
#pragma unroll
    for (int nt = 0; nt < 4; ++nt) {
        int col = w * 16 + nt * 64 + lane16;
        float bv = bias[col];
#pragma unroll
        for (int mt = 0; mt < 4; ++mt)
#pragma unroll
            for (int reg = 0; reg < 4; ++reg) {
                int row = mt * 16 + quad * 4 + reg;
                if (row0 + row < M)
                    C[(size_t)(row0 + row) * H + col] = f2bf(acc[mt][nt][reg] + bv);
            }
    }
}

// ---------------- MFMA node GEMM: vp = v_in @ Lv_w^T (Lv_b cancels in BN) ----------------
template <bool W16>
__global__ __launch_bounds__(256, 2) void k_node_mfma(
    const u16* __restrict__ A, const u16* __restrict__ wb, const float* __restrict__ wf,
    u16* __restrict__ C)
{
    __shared__ u16 As[64][264];
    int t = threadIdx.x;
    int row0 = blockIdx.x * 64;
    int rows = min(64, N - row0);
    int r = t >> 2, q = t & 3;
    if (r < rows) {
        const u16* gp = A + (size_t)(row0 + r) * H + q * 64;
#pragma unroll
        for (int i = 0; i < 16; ++i)
            *(ushort4*)&As[r][q * 64 + i * 4] = *(const ushort4*)(gp + i * 4);
    } else {
#pragma unroll
        for (int i = 0; i < 16; ++i) *(ushort4*)&As[r][q * 64 + i * 4] = make_ushort4(0, 0, 0, 0);
    }
    __syncthreads();
    int w = t >> 6, l = t & 63, lane16 = l & 15, quad = l >> 4;
    f32x4 acc[4][4];
#pragma unroll
    for (int i = 0; i < 4; ++i)
#pragma unroll
        for (int j = 0; j < 4; ++j) acc[i][j] = (f32x4){0.f, 0.f, 0.f, 0.f};
    for (int k0 = 0; k0 < H; k0 += 32) {
        bf16x8 a[4], b[4];
#pragma unroll
        for (int mt = 0; mt < 4; ++mt)
            a[mt] = *(const bf16x8*)&As[mt * 16 + lane16][k0 + quad * 8];
#pragma unroll
        for (int nt = 0; nt < 4; ++nt)
            b[nt] = ldb<W16>(wb, wf, (size_t)(w * 16 + nt * 64 + lane16) * H + k0 + quad * 8);
#pragma unroll
        for (int mt = 0; mt < 4; ++mt)
#pragma unroll
            for (int nt = 0; nt < 4; ++nt)
                acc[mt][nt] = __builtin_amdgcn_mfma_f32_16x16x32_bf16(a[mt], b[nt], acc[mt][nt], 0, 0, 0);
    }
#pragma unroll
    for (int nt = 0; nt < 4; ++nt) {
        int col = w * 16 + nt * 64 + lane16;
#pragma unroll
        for (int mt = 0; mt < 4; ++mt)
#pragma unroll
            for (int reg = 0; reg < 4; ++reg) {
                int row = mt * 16 + quad * 4 + reg;
                if (row < rows)
                    C[(size_t)(row0 + row) * H + col] = f2bf(acc[mt][nt][reg]);
            }
    }
}

// ---------------- MFMA edge pass v3: M-tile 32, 4 blocks/CU ----------------
// raw[e][n] = (e_in @ Le_w^T)[e][n] + vp[src_e][n] + vp[dst_e][n]
// FIRST (dst CSR): BN stats (quad-shuffle -> 64-slice global atomics) + raw segmented max.
// !FIRST (src CSR): raw segmented max + e_in += relu(affine(raw)) (tile owns its rows).
// Wave w covers cols [w*64, w*64+64): col = w*64 + nt*16 + lane16; rows = mt*16 + quad*4 + reg.
template <bool FIRST>
__global__ __launch_bounds__(256, 4) void k_edge_mfma(
    const u16* __restrict__ ein, const u16* __restrict__ wbf,
    const u16* __restrict__ vp, const int* __restrict__ src, const int* __restrict__ dst,
    const int* __restrict__ adj, const int* __restrict__ endo,
    unsigned int* __restrict__ vie, double* __restrict__ stats_e,
    const float* __restrict__ scale, const float* __restrict__ shift,
    u16* __restrict__ ein_rw)
{
    __shared__ u16 As[32][264];      // K-loop A tile; aliased as praw afterwards
    __shared__ u16 Us[32][264];      // vp[src]+vp[dst]
    __shared__ int s_edge[32];
    __shared__ int s_node[32];
    u16 (*praw)[264] = As;

    int t = threadIdx.x;
    int p0 = blockIdx.x * 32;
    if (t < 32) {
        int e = adj[p0 + t];
        s_edge[t] = e;
        int lo = 0, hi = N - 1, p = p0 + t;
        while (lo < hi) { int mid = (lo + hi) >> 1; if (endo[mid] > p) hi = mid; else lo = mid + 1; }
        s_node[t] = lo;
    }
    __syncthreads();
    int r = t >> 3, q = t & 7;       // r: row 0..31, q: 32-col chunk 0..7
    {
        int e = s_edge[r];
        const u16* gp = ein + (size_t)e * H + q * 32;
        const u16* vs = vp + (size_t)src[e] * H + q * 32;
        const u16* vd = vp + (size_t)dst[e] * H + q * 32;
#pragma unroll
        for (int i = 0; i < 8; ++i)
            *(ushort4*)&As[r][q * 32 + i * 4] = *(const ushort4*)(gp + i * 4);
#pragma unroll
        for (int i = 0; i < 8; ++i) {
            ushort4 a4 = *(const ushort4*)(vs + i * 4);
            ushort4 b4 = *(const ushort4*)(vd + i * 4);
            *(ushort4*)&Us[r][q * 32 + i * 4] = make_ushort4(
                f2bf(bf2f(a4.x) + bf2f(b4.x)), f2bf(bf2f(a4.y) + bf2f(b4.y)),
                f2bf(bf2f(a4.z) + bf2f(b4.z)), f2bf(bf2f(a4.w) + bf2f(b4.w)));
        }
    }
    __syncthreads();

    int w = t >> 6, l = t & 63, lane16 = l & 15, quad = l >> 4;
    f32x4 acc[2][4];
#pragma unroll
    for (int i = 0; i < 2; ++i)
#pragma unroll
        for (int j = 0; j < 4; ++j) acc[i][j] = (f32x4){0.f, 0.f, 0.f, 0.f};
    const u16* wb0 = wbf + (size_t)(w * 64 + lane16) * H + quad * 8;
    for (int k0 = 0; k0 < H; k0 += 32) {
        bf16x8 a[2], b[4];
#pragma unroll
        for (int mt = 0; mt < 2; ++mt)
            a[mt] = *(const bf16x8*)&As[mt * 16 + lane16][k0 + quad * 8];
#pragma unroll
        for (int nt = 0; nt < 4; ++nt)
            b[nt] = *(const bf16x8*)(wb0 + (size_t)nt * 16 * H + k0);
#pragma unroll
        for (int mt = 0; mt < 2; ++mt)
#pragma unroll
            for (int nt = 0; nt < 4; ++nt)
                acc[mt][nt] = __builtin_amdgcn_mfma_f32_16x16x32_bf16(a[mt], b[nt], acc[mt][nt], 0, 0, 0);
    }
    __syncthreads();   // As reads complete -> region becomes praw

#pragma unroll
    for (int nt = 0; nt < 4; ++nt) {
        int col = w * 64 + nt * 16 + lane16;
        float s = 0.f, qq = 0.f;
#pragma unroll
        for (int mt = 0; mt < 2; ++mt)
#pragma unroll
            for (int reg = 0; reg < 4; ++reg) {
                int row = mt * 16 + quad * 4 + reg;
                float v = acc[mt][nt][reg] + bf2f(Us[row][col]);
                praw[row][col] = f2bf(v);
                if (FIRST) { s += v; qq += v * v; }
            }
        if (FIRST) {
            s  += __shfl_xor(s, 16, 64);  s  += __shfl_xor(s, 32, 64);
            qq += __shfl_xor(qq, 16, 64); qq += __shfl_xor(qq, 32, 64);
            if (quad == 0) {
                int slice = blockIdx.x & 63;
                atomicAdd(&stats_e[(size_t)slice * 512 + col], (double)s);
                atomicAdd(&stats_e[(size_t)slice * 512 + 256 + col], (double)qq);
            }
        }
    }
    __syncthreads();
    // segmented max walk over node runs: thread t owns column t
    {
        int cur = s_node[0];
        float m = bf2f(praw[0][t]);
        for (int rr = 1; rr < 32; ++rr) {
            int nd = s_node[rr];
            float v = bf2f(praw[rr][t]);
            if (nd != cur) {
                atomicMax(&vie[(size_t)cur * H + t], encf(m));
                cur = nd; m = v;
            } else m = fmaxf(m, v);
        }
        atomicMax(&vie[(size_t)cur * H + t], encf(m));
    }
    if (!FIRST) {
        u16* gp = ein_rw + (size_t)s_edge[r] * H + q * 32;
        const float* scp = scale + q * 32;
        const float* shp = shift + q * 32;
#pragma unroll
        for (int i = 0; i < 8; ++i) {
            int c = q * 32 + i * 4;
            ushort2 pa = *(const ushort2*)&praw[r][c];
            ushort2 pb = *(const ushort2*)&praw[r][c + 2];
            float4 sc = *(const float4*)(scp + i * 4);
            float4 sh = *(const float4*)(shp + i * 4);
            ushort4 ev = *(const ushort4*)(gp + i * 4);
            float o0 = bf2f(ev.x) + fmaxf(fmaf(bf2f(pa.x), sc.x, sh.x), 0.f);
            float o1 = bf2f(ev.y) + fmaxf(fmaf(bf2f(pa.y), sc.y, sh.y), 0.f);
            float o2 = bf2f(ev.z) + fmaxf(fmaf(bf2f(pb.x), sc.z, sh.z), 0.f);
            float o3 = bf2f(ev.w) + fmaxf(fmaf(bf2f(pb.y), sc.w, sh.w), 0.f);
            *(ushort4*)(gp + i * 4) = make_ushort4(f2bf(o0), f2bf(o1), f2bf(o2), f2bf(o3));
        }
    }
}

// ---------------- BN finalize (edge: 64-slice reduce) ----------------
__global__ void k_bn_final_e(const double* __restrict__ stats_e,
                             const float* __restrict__ g, const float* __restrict__ b,
                             float* __restrict__ scale, float* __restrict__ shift) {
    int j = threadIdx.x;
    double m = 0.0, q = 0.0;
    for (int s = 0; s < 64; ++s) {
        m += stats_e[(size_t)s * 512 + j];
        q += stats_e[(size_t)s * 512 + 256 + j];
    }
    m /= (double)E;
    double var = q / (double)E - m * m;
    if (var < 0.0) var = 0.0;
    float inv = rsqrtf((float)var + 1e-5f);
    float sc = g[j] * inv;
    scale[j] = sc;
    shift[j] = b[j] - (float)m * sc;
}

// ---------------- BN finalize (node, single slice) ----------------
__global__ void k_bn_final(const double* __restrict__ stats, int base,
                           const float* __restrict__ g, const float* __restrict__ b,
                           double cnt, float* __restrict__ scale, float* __restrict__ shift) {
    int j = threadIdx.x;
    double m = stats[base + j] / cnt;
    double var = stats[base + 256 + j] / cnt - m * m;
    if (var < 0.0) var = 0.0;
    float inv = rsqrtf((float)var + 1e-5f);
    float sc = g[j] * inv;
    scale[j] = sc;
    shift[j] = b[j] - (float)m * sc;
}

// ---------------- vie finalize: decode raw max, affine+relu; untouched (isolated) -> 0 ----------------
__global__ void k_vie_final(unsigned int* __restrict__ vie_u,
                            const float* __restrict__ scale, const float* __restrict__ shift) {
    size_t idx = ((size_t)blockIdx.x * 256 + threadIdx.x) * 4;
    int col = (int)(idx & (size_t)(H - 1));
    uint4 u = *(const uint4*)(vie_u + idx);
    float4 sc = *(const float4*)(scale + col);
    float4 sh = *(const float4*)(shift + col);
    float4 o;
    o.x = (u.x == 0u) ? 0.f : fmaxf(fmaf(decf(u.x), sc.x, sh.x), 0.f);
    o.y = (u.y == 0u) ? 0.f : fmaxf(fmaf(decf(u.y), sc.y, sh.y), 0.f);
    o.z = (u.z == 0u) ? 0.f : fmaxf(fmaf(decf(u.z), sc.z, sh.z), 0.f);
    o.w = (u.w == 0u) ? 0.f : fmaxf(fmaf(decf(u.w), sc.w, sh.w), 0.f);
    *(float4*)((float*)vie_u + idx) = o;
}

// ---------------- MFMA fused GRU: h = (1-z)*n + z*v_in, plus BN stats ----------------
template <bool W16>
__global__ __launch_bounds__(256, 2) void k_gru_mfma(
    const float* __restrict__ vie, const u16* __restrict__ vin,
    const u16* __restrict__ wihb, const float* __restrict__ wihf,
    const u16* __restrict__ whhb, const float* __restrict__ whhf,
    const float* __restrict__ bih, const float* __restrict__ bhh,
    u16* __restrict__ hout, double* __restrict__ stats_v)
{
    __shared__ u16 Ae[64][264];   // vie (bf16-staged)
    __shared__ u16 Av[64][264];   // vin
    __shared__ float csum[256], csq[256];
    int t = threadIdx.x;
    int row0 = blockIdx.x * 64;
    int rows = min(64, N - row0);
    int r = t >> 2, q = t & 3;
    if (r < rows) {
        const float* gp = vie + (size_t)(row0 + r) * H + q * 64;
        const u16* hp = vin + (size_t)(row0 + r) * H + q * 64;
#pragma unroll
        for (int i = 0; i < 16; ++i) {
            float4 v = *(const float4*)(gp + i * 4);
            *(ushort4*)&Ae[r][q * 64 + i * 4] = make_ushort4(f2bf(v.x), f2bf(v.y), f2bf(v.z), f2bf(v.w));
            *(ushort4*)&Av[r][q * 64 + i * 4] = *(const ushort4*)(hp + i * 4);
        }
    } else {
#pragma unroll
        for (int i = 0; i < 16; ++i) {
            *(ushort4*)&Ae[r][q * 64 + i * 4] = make_ushort4(0, 0, 0, 0);
            *(ushort4*)&Av[r][q * 64 + i * 4] = make_ushort4(0, 0, 0, 0);
        }
    }
    __syncthreads();
    int w = t >> 6, l = t & 63, lane16 = l & 15, quad = l >> 4;

    for (int g = 0; g < 4; ++g) {
        int j = g * 64 + w * 16 + lane16;
        f32x4 aR[4], aZ[4], aIG[4], aHG[4];
#pragma unroll
        for (int mt = 0; mt < 4; ++mt) {
            aR[mt] = (f32x4){0.f, 0.f, 0.f, 0.f};  aZ[mt] = (f32x4){0.f, 0.f, 0.f, 0.f};
            aIG[mt] = (f32x4){0.f, 0.f, 0.f, 0.f}; aHG[mt] = (f32x4){0.f, 0.f, 0.f, 0.f};
        }
        for (int k0 = 0; k0 < H; k0 += 32) {
            size_t kq = (size_t)k0 + quad * 8;
            bf16x8 ae[4], av[4];
#pragma unroll
            for (int mt = 0; mt < 4; ++mt) {
                ae[mt] = *(const bf16x8*)&Ae[mt * 16 + lane16][k0 + quad * 8];
                av[mt] = *(const bf16x8*)&Av[mt * 16 + lane16][k0 + quad * 8];
            }
            bf16x8 bri = ldb<W16>(wihb, wihf, (size_t)j * H + kq);
            bf16x8 bzi = ldb<W16>(wihb, wihf, (size_t)(H + j) * H + kq);
            bf16x8 bgi = ldb<W16>(wihb, wihf, (size_t)(2 * H + j) * H + kq);
            bf16x8 brh = ldb<W16>(whhb, whhf, (size_t)j * H + kq);
            bf16x8 bzh = ldb<W16>(whhb, whhf, (size_t)(H + j) * H + kq);
            bf16x8 bgh = ldb<W16>(whhb, whhf, (size_t)(2 * H + j) * H + kq);
#pragma unroll
            for (int mt = 0; mt < 4; ++mt) {
                aR[mt]  = __builtin_amdgcn_mfma_f32_16x16x32_bf16(ae[mt], bri, aR[mt], 0, 0, 0);
                aR[mt]  = __builtin_amdgcn_mfma_f32_16x16x32_bf16(av[mt], brh, aR[mt], 0, 0, 0);
                aZ[mt]  = __builtin_amdgcn_mfma_f32_16x16x32_bf16(ae[mt], bzi, aZ[mt], 0, 0, 0);
                aZ[mt]  = __builtin_amdgcn_mfma_f32_16x16x32_bf16(av[mt], bzh, aZ[mt], 0, 0, 0);
                aIG[mt] = __builtin_amdgcn_mfma_f32_16x16x32_bf16(ae[mt], bgi, aIG[mt], 0, 0, 0);
                aHG[mt] = __builtin_amdgcn_mfma_f32_16x16x32_bf16(av[mt], bgh, aHG[mt], 0, 0, 0);
            }
        }
        float br_ = bih[j] + bhh[j];
        float bz_ = bih[H + j] + bhh[H + j];
        float bgi_ = bih[2 * H + j];
        float bgh_ = bhh[2 * H + j];
        float s = 0.f, qq = 0.f;
#pragma unroll
        for (int mt = 0; mt < 4; ++mt)
#pragma unroll
            for (int reg = 0; reg < 4; ++reg) {
                int row = mt * 16 + quad * 4 + reg;
                float rr = sigmf(aR[mt][reg] + br_);
                float zz = sigmf(aZ[mt][reg] + bz_);
                float nn = tanhf_(aIG[mt][reg] + bgi_ + rr * (aHG[mt][reg] + bgh_));
                float vv = bf2f(Av[row][j]);
                float hv = (1.f - zz) * nn + zz * vv;
                if (row < rows) {
                    hout[(size_t)(row0 + row) * H + j] = f2bf(hv);
                    s += hv; qq += hv * hv;
                }
            }
        s  += __shfl_xor(s, 16, 64);  s  += __shfl_xor(s, 32, 64);
        qq += __shfl_xor(qq, 16, 64); qq += __shfl_xor(qq, 32, 64);
        if (quad == 0) { csum[j] = s; csq[j] = qq; }
    }
    __syncthreads();
    atomicAdd(&stats_v[t], (double)csum[t]);
    atomicAdd(&stats_v[256 + t], (double)csq[t]);
}

// ---------------- vertex update: v_in += relu(h*scale+shift) (bf16 rmw) ----------------
__global__ void k_vertex_update(u16* __restrict__ vin, const u16* __restrict__ h,
                                const float* __restrict__ scale, const float* __restrict__ shift) {
    size_t idx = ((size_t)blockIdx.x * 256 + threadIdx.x) * 4;
    int col = (int)(idx & (size_t)(H - 1));
    ushort4 hv = *(const ushort4*)(h + idx);
    float4 sc = *(const float4*)(scale + col);
    float4 sh = *(const float4*)(shift + col);
    ushort4 vv = *(const ushort4*)(vin + idx);
    float o0 = bf2f(vv.x) + fmaxf(fmaf(bf2f(hv.x), sc.x, sh.x), 0.f);
    float o1 = bf2f(vv.y) + fmaxf(fmaf(bf2f(hv.y), sc.y, sh.y), 0.f);
    float o2 = bf2f(vv.z) + fmaxf(fmaf(bf2f(hv.z), sc.z, sh.z), 0.f);
    float o3 = bf2f(vv.w) + fmaxf(fmaf(bf2f(hv.w), sc.w, sh.w), 0.f);
    *(ushort4*)(vin + idx) = make_ushort4(f2bf(o0), f2bf(o1), f2bf(o2), f2bf(o3));
}

// ---------------- final: out[e] = e_in[e] . w_fo + b_fo ----------------
__global__ __launch_bounds__(256) void k_final(const u16* __restrict__ ein,
                                               const float* __restrict__ w_fo, float* __restrict__ out) {
    int t = threadIdx.x;
    int lane = t & 63;
    int w = (blockIdx.x << 2) + (t >> 6);
    float4 wv = *(const float4*)(w_fo + lane * 4);
    float bfo = w_fo[H];
    int e0 = w * 64;
    for (int e = e0; e < e0 + 64; ++e) {
        ushort4 u = *(const ushort4*)(ein + (size_t)e * H + lane * 4);
        float p = bf2f(u.x) * wv.x + bf2f(u.y) * wv.y + bf2f(u.z) * wv.z + bf2f(u.w) * wv.w;
        for (int off = 32; off > 0; off >>= 1) p += __shfl_down(p, off, 64);
        if (lane == 0) out[e] = p + bfo;
    }
}

// ---------------- pipeline ----------------
template <bool W16>
static void run_all(void* const* d_in, void* d_out, void* d_ws, hipStream_t stream) {
    const float* x         = (const float*)d_in[0];
    const float* edge_attr = (const float*)d_in[1];
    const int*   ei        = (const int*)d_in[2];
    const int*   src = ei;
    const int*   dst = ei + E;
    const float* ew  = (const float*)d_in[3];
    const float* eb  = (const float*)d_in[4];
    const float* vw  = (const float*)d_in[5];
    const float* vb  = (const float*)d_in[6];
    const float* Le_w = (const float*)d_in[7];
    // d_in[8] = Le_b : cancels in BN
    const float* Lv_w = (const float*)d_in[9];
    // d_in[10] = Lv_b : cancels in BN
    const float* bne_g = (const float*)d_in[11];
    const float* bne_b = (const float*)d_in[12];
    const float* bnv_g = (const float*)d_in[13];
    const float* bnv_b = (const float*)d_in[14];
    const float* gwih  = (const float*)d_in[15];
    const float* gwhh  = (const float*)d_in[16];
    const float* gbih  = (const float*)d_in[17];
    const float* gbhh  = (const float*)d_in[18];
    const float* fin_w = (const float*)d_in[19];
    const float* fin_b = (const float*)d_in[20];
    const float* out_w = (const float*)d_in[21];
    const float* out_b = (const float*)d_in[22];
    float* out = (float*)d_out;

    const size_t nh = (size_t)N * H, eh = (size_t)E * H;
    char* base = (char*)d_ws;
    size_t off = 0;
    auto alloc = [&](size_t bytes) -> char* {
        char* p = base + off;
        off = (off + bytes + 255) & ~(size_t)255;
        return p;
    };
    float* w_fo = (float*)alloc((H + 1) * sizeof(float));
    u16* v_in = (u16*)alloc(nh * sizeof(u16));
    u16* vp   = (u16*)alloc(nh * sizeof(u16));          // aliased as hbuf after edge passes
    unsigned int* vie_u = (unsigned int*)alloc(nh * sizeof(unsigned int));
    u16* e_in = (u16*)alloc(eh * sizeof(u16));
    u16* wbf  = (u16*)alloc((size_t)NL * H * H * sizeof(u16));   // Le_w bf16 (always)
    double* stats_e = (double*)alloc((size_t)64 * 512 * sizeof(double));
    double* stats_v = (double*)alloc(512 * sizeof(double));
    float* scale_e = (float*)alloc(H * sizeof(float));
    float* shift_e = (float*)alloc(H * sizeof(float));
    float* scale_v = (float*)alloc(H * sizeof(float));
    float* shift_v = (float*)alloc(H * sizeof(float));
    int* curS = (int*)alloc((size_t)N * sizeof(int));
    int* curD = (int*)alloc((size_t)N * sizeof(int));
    int* adjS = (int*)alloc((size_t)E * sizeof(int));
    int* adjD = (int*)alloc((size_t)E * sizeof(int));
    // optional bf16 weight copies (only consumed when W16)
    u16 *wbf_v = nullptr, *wbf_ih = nullptr, *wbf_hh = nullptr, *ew_b = nullptr, *vw_b = nullptr;
    if (W16) {
        wbf_v  = (u16*)alloc((size_t)NL * H * H * sizeof(u16));
        wbf_ih = (u16*)alloc((size_t)NL * 3 * H * H * sizeof(u16));
        wbf_hh = (u16*)alloc((size_t)NL * 3 * H * H * sizeof(u16));
        ew_b   = (u16*)alloc((size_t)H * FEAT * sizeof(u16));
        vw_b   = (u16*)alloc((size_t)H * FEAT * sizeof(u16));
    }
    u16* hbuf = vp;  // vp dead after edge passes; GRU writes here

    // fused final weights; bf16 weight conversions
    k_fuse_final<<<1, 256, 0, stream>>>(fin_w, fin_b, out_w, out_b, w_fo);
    k_cvt_w<<<(NL * H * H / 4 + 255) / 256, 256, 0, stream>>>(Le_w, wbf, NL * H * H / 4);
    if (W16) {
        k_cvt_w<<<(NL * H * H / 4 + 255) / 256, 256, 0, stream>>>(Lv_w, wbf_v, NL * H * H / 4);
        k_cvt_w<<<(NL * 3 * H * H / 4 + 255) / 256, 256, 0, stream>>>(gwih, wbf_ih, NL * 3 * H * H / 4);
        k_cvt_w<<<(NL * 3 * H * H / 4 + 255) / 256, 256, 0, stream>>>(gwhh, wbf_hh, NL * 3 * H * H / 4);
        k_cvt_w<<<(H * FEAT / 4 + 255) / 256, 256, 0, stream>>>(ew, ew_b, H * FEAT / 4);
        k_cvt_w<<<(H * FEAT / 4 + 255) / 256, 256, 0, stream>>>(vw, vw_b, H * FEAT / 4);
    }
    // dual CSR
    k_zero_int<<<(N + 255) / 256, 256, 0, stream>>>(curS, N);
    k_zero_int<<<(N + 255) / 256, 256, 0, stream>>>(curD, N);
    k_hist2<<<E / 256, 256, 0, stream>>>(src, dst, curS, curD);
    k_scan<<<1, 256, 0, stream>>>(curS);
    k_scan<<<1, 256, 0, stream>>>(curD);
    k_fill_pair<<<E / 256, 256, 0, stream>>>(src, dst, curS, curD, adjS, adjD);
    // input projections (MFMA, bf16 out)
    const int ntile = (N + 63) / 64;
    k_proj_mfma<W16><<<ntile, 256, 0, stream>>>(x, vw_b, vw, vb, v_in, N);
    k_proj_mfma<W16><<<E / 64, 256, 0, stream>>>(edge_attr, ew_b, ew, eb, e_in, E);

    const int nstat = 64 * 512 + 512;
    for (int k = 0; k < NL; ++k) {
        k_zero_f64<<<(nstat + 255) / 256, 256, 0, stream>>>(stats_e, nstat);  // stats_v contiguous after
        k_fill_u32<<<(int)(nh / 4 / 256), 256, 0, stream>>>(vie_u, 0u);
        k_node_mfma<W16><<<ntile, 256, 0, stream>>>(v_in,
            W16 ? wbf_v + (size_t)k * H * H : nullptr, Lv_w + (size_t)k * H * H, vp);
        // dst pass: stats + raw max
        k_edge_mfma<true><<<E / 32, 256, 0, stream>>>(e_in, wbf + (size_t)k * H * H, vp, src, dst,
                                                      adjD, curD, vie_u, stats_e, nullptr, nullptr, nullptr);
        k_bn_final_e<<<1, 256, 0, stream>>>(stats_e, bne_g + k * H, bne_b + k * H, scale_e, shift_e);
        // src pass: raw max + residual into e_in
        k_edge_mfma<false><<<E / 32, 256, 0, stream>>>(e_in, wbf + (size_t)k * H * H, vp, src, dst,
                                                       adjS, curS, vie_u, nullptr, scale_e, shift_e, e_in);
        k_vie_final<<<(int)(nh / 4 / 256), 256, 0, stream>>>(vie_u, scale_e, shift_e);
        k_gru_mfma<W16><<<ntile, 256, 0, stream>>>((const float*)vie_u, v_in,
            W16 ? wbf_ih + (size_t)k * 3 * H * H : nullptr, gwih + (size_t)k * 3 * H * H,
            W16 ? wbf_hh + (size_t)k * 3 * H * H : nullptr, gwhh + (size_t)k * 3 * H * H,
            gbih + (size_t)k * 3 * H, gbhh + (size_t)k * 3 * H, hbuf, stats_v);
        k_bn_final<<<1, 256, 0, stream>>>(stats_v, 0, bnv_g + k * H, bnv_b + k * H, (double)N, scale_v, shift_v);
        k_vertex_update<<<(int)(nh / 4 / 256), 256, 0, stream>>>(v_in, hbuf, scale_v, shift_v);
    }
    k_final<<<E / 256, 256, 0, stream>>>(e_in, w_fo, out);
}

// ---------------- host entry ----------------
extern "C" void kernel_launch(void* const* d_in, const int* in_sizes, int n_in,
                              void* d_out, int out_size, void* d_ws, size_t ws_size,
                              hipStream_t stream) {
    (void)in_sizes; (void)n_in; (void)out_size;
    const size_t nh = (size_t)N * H, eh = (size_t)E * H;
    auto rup = [](size_t x) { return (x + 255) & ~(size_t)255; };
    size_t need_base = rup((H + 1) * 4) + 2 * rup(nh * 2) + rup(nh * 4) + rup(eh * 2)
                     + rup((size_t)NL * H * H * 2) + rup((size_t)64 * 512 * 8) + rup(512 * 8)
                     + 4 * rup(H * 4) + 2 * rup((size_t)N * 4) + 2 * rup((size_t)E * 4);
    size_t need_full = need_base + rup((size_t)NL * H * H * 2)
                     + 2 * rup((size_t)NL * 3 * H * H * 2) + 2 * rup((size_t)H * FEAT * 2);
    if (ws_size == 0 || ws_size >= need_full)
        run_all<true>(d_in, d_out, d_ws, stream);   // bf16 weight copies fit
    else
        run_all<false>(d_in, d_out, d_ws, stream);  // inline fp32->bf16 B-fragment converts
}